// Round 20
// baseline (227.042 us; speedup 1.0000x reference)
//
#include <hip/hip_runtime.h>

#define B_    32
#define C_    192
#define N_    784
#define NP_   1024        // sqp row stride (pad never read)
#define K_    9
#define COUT_ 384
#define NPTS_ (B_ * N_)   // 25088
#define NTILES_ 224       // 32 b * 7 ntiles
#define DKW_  836         // dkS row stride (>= 13*64=832)

typedef __attribute__((ext_vector_type(8))) short short8;   // 8 bf16 = 4 VGPR
typedef __attribute__((ext_vector_type(4))) float f32x4;    // MFMA acc

// ordered-uint transform: monotone map float -> uint
__device__ __forceinline__ unsigned int ford(float f) {
  unsigned int u = __float_as_uint(f);
  return u ^ ((u & 0x80000000u) ? 0xFFFFFFFFu : 0x80000000u);
}
// fp32 -> bf16 (RNE)
__device__ __forceinline__ unsigned short f2bf(float f) {
  unsigned int u = __float_as_uint(f);
  u += 0x7FFFu + ((u >> 16) & 1u);
  return (unsigned short)(u >> 16);
}
__device__ __forceinline__ float bf2f(unsigned short h) {
  return __uint_as_float(((unsigned int)h) << 16);
}

// ---------------------------------------------------------------------------
// K1: norm + FUSED frag pack (proven R17). Block = 64 pts x 4 c-groups.
// ---------------------------------------------------------------------------
__global__ __launch_bounds__(256) void norm_kernel(
    const float* __restrict__ x, short8* __restrict__ fragH,
    short8* __restrict__ fragL, float* __restrict__ sqp) {
  int t = threadIdx.x;
  int pl = t & 63, cg = t >> 6;
  int p = blockIdx.x * 64 + pl;
  int b = p / N_, n = p % N_;
  const float* xb = x + (size_t)b * C_ * N_ + n;

  __shared__ float red[4][64];
  __shared__ float nrmS[64];

  float part = 0.f;
  #pragma unroll 8
  for (int j = 0; j < 48; j++) {
    float v = xb[(size_t)(cg * 48 + j) * N_];
    part = __fmaf_rn(v, v, part);
  }
  red[cg][pl] = part;
  __syncthreads();
  if (t < 64) {
    float ssq = __fadd_rn(__fadd_rn(red[0][t], red[1][t]),
                          __fadd_rn(red[2][t], red[3][t]));
    nrmS[t] = fmaxf(__fsqrt_rn(ssq), 1e-12f);
  }
  __syncthreads();
  float nrm = nrmS[pl];
  int g = n >> 4, li = n & 15;
  float p2 = 0.f;
  #pragma unroll
  for (int s = 0; s < 6; s++) {
    int kslot = cg * 6 + s;          // 0..23
    int ks = kslot >> 2, kq = kslot & 3;
    union { short8 v; unsigned short u[8]; } ph, plo;
    #pragma unroll
    for (int j = 0; j < 8; j++) {
      float a = __fdiv_rn(xb[(size_t)(kslot * 8 + j) * N_], nrm);
      unsigned short h = f2bf(a);
      ph.u[j]  = h;
      plo.u[j] = f2bf(__fsub_rn(a, bf2f(h)));
      p2 = __fmaf_rn(a, a, p2);
    }
    size_t idx = (((size_t)b * 6 + ks) * 64 + g) * 64 + (kq * 16 + li);
    fragH[idx] = ph.v;
    fragL[idx] = plo.v;
  }
  red[cg][pl] = p2;
  __syncthreads();
  if (t < 64) {
    float sq = __fadd_rn(__fadd_rn(red[0][t], red[1][t]),
                         __fadd_rn(red[2][t], red[3][t]));
    int pp = blockIdx.x * 64 + t;
    sqp[(size_t)(pp / N_) * NP_ + (pp % N_)] = sq;
  }
}

// ---------------------------------------------------------------------------
// K2: MFMA KNN, 32 queries/block (2 row-groups), 512 thr = 8 waves,
//  dkS[32] rows: ALL distances go straight to LDS (no held keys — the R14
//  VGPR trap avoided). B-panel read once per 32 queries (0.53x traffic).
//  Distance chains bit-identical to R19 for every (query, candidate).
//  Wave group ranges over 49 groups: w0: 0-6 (7), w1..w7: 6 each.
// ---------------------------------------------------------------------------
__global__ __launch_bounds__(512) void knn_kernel(
    const short8* __restrict__ fragH, const short8* __restrict__ fragL,
    const float* __restrict__ sqp, int* __restrict__ nn9) {
  int wg = blockIdx.x;                 // 800 = 8 xcd * (4 b * 25 qt)
  int r = wg & 7, j = wg >> 3;
  int b  = r + 8 * (j / 25);
  int qt = j % 25;
  int q0 = qt * 32;
  int t = threadIdx.x, lane = t & 63, w = t >> 6;   // w in [0,8)

  __shared__ unsigned int dkS[32][DKW_];  // 107 KB keys
  __shared__ float qsqS[32];

  // preset pad cols [784, 836) to MAX for all 32 rows
  for (int i = t; i < 32 * 52; i += 512)
    dkS[i / 52][784 + i % 52] = 0xFFFFFFFFu;
  if (t < 32) qsqS[t] = sqp[(size_t)b * NP_ + q0 + t];
  __syncthreads();

  const float* sqb = sqp + (size_t)b * NP_;
  const short8* fH = fragH + (size_t)b * 6 * 64 * 64;
  const short8* fL = fragL + (size_t)b * 6 * 64 * 64;

  int ga0 = qt * 2;
  int ga1 = (qt * 2 + 1 > 48) ? 48 : (qt * 2 + 1);  // qt=24: dup, discarded

  short8 aH0[6], aL0[6], aH1[6], aL1[6];
  #pragma unroll
  for (int ks = 0; ks < 6; ks++) {
    aH0[ks] = fH[((size_t)ks * 64 + ga0) * 64 + lane];
    aL0[ks] = fL[((size_t)ks * 64 + ga0) * 64 + lane];
    aH1[ks] = fH[((size_t)ks * 64 + ga1) * 64 + lane];
    aL1[ks] = fL[((size_t)ks * 64 + ga1) * 64 + lane];
  }

  int colL = lane & 15, rq = lane >> 4;
  int wstart = (w == 0) ? 0 : 7 + (w - 1) * 6;
  int wend   = wstart + ((w == 0) ? 7 : 6);

  int g = wstart;
  for (; g + 1 < wend; g += 2) {
    int g0 = g, g1 = g + 1;
    f32x4 z = {0.f, 0.f, 0.f, 0.f};
    f32x4 c00h = z, c00l = z, c00x = z, c01h = z, c01l = z, c01x = z;
    f32x4 c10h = z, c10l = z, c10x = z, c11h = z, c11l = z, c11x = z;
    #pragma unroll
    for (int ks = 0; ks < 6; ks++) {
      short8 b0h = fH[((size_t)ks * 64 + g0) * 64 + lane];
      short8 b0l = fL[((size_t)ks * 64 + g0) * 64 + lane];
      short8 b1h = fH[((size_t)ks * 64 + g1) * 64 + lane];
      short8 b1l = fL[((size_t)ks * 64 + g1) * 64 + lane];
      c00h = __builtin_amdgcn_mfma_f32_16x16x32_bf16(aH0[ks], b0h, c00h, 0, 0, 0);
      c00l = __builtin_amdgcn_mfma_f32_16x16x32_bf16(aH0[ks], b0l, c00l, 0, 0, 0);
      c00x = __builtin_amdgcn_mfma_f32_16x16x32_bf16(aL0[ks], b0h, c00x, 0, 0, 0);
      c01h = __builtin_amdgcn_mfma_f32_16x16x32_bf16(aH0[ks], b1h, c01h, 0, 0, 0);
      c01l = __builtin_amdgcn_mfma_f32_16x16x32_bf16(aH0[ks], b1l, c01l, 0, 0, 0);
      c01x = __builtin_amdgcn_mfma_f32_16x16x32_bf16(aL0[ks], b1h, c01x, 0, 0, 0);
      c10h = __builtin_amdgcn_mfma_f32_16x16x32_bf16(aH1[ks], b0h, c10h, 0, 0, 0);
      c10l = __builtin_amdgcn_mfma_f32_16x16x32_bf16(aH1[ks], b0l, c10l, 0, 0, 0);
      c10x = __builtin_amdgcn_mfma_f32_16x16x32_bf16(aL1[ks], b0h, c10x, 0, 0, 0);
      c11h = __builtin_amdgcn_mfma_f32_16x16x32_bf16(aH1[ks], b1h, c11h, 0, 0, 0);
      c11l = __builtin_amdgcn_mfma_f32_16x16x32_bf16(aH1[ks], b1l, c11l, 0, 0, 0);
      c11x = __builtin_amdgcn_mfma_f32_16x16x32_bf16(aL1[ks], b1h, c11x, 0, 0, 0);
    }
    float cs0 = sqb[g0 * 16 + colL];
    float cs1 = sqb[g1 * 16 + colL];
    #pragma unroll
    for (int rr = 0; rr < 4; rr++) {
      int row = rq * 4 + rr;
      float qs0 = qsqS[row];
      float g0v = __fadd_rn(__fadd_rn(c00h[rr], c00l[rr]), c00x[rr]);
      float g1v = __fadd_rn(__fadd_rn(c01h[rr], c01l[rr]), c01x[rr]);
      dkS[row][g0 * 16 + colL] =
          ford(__fadd_rn(__fsub_rn(qs0, __fmul_rn(2.0f, g0v)), cs0));
      dkS[row][g1 * 16 + colL] =
          ford(__fadd_rn(__fsub_rn(qs0, __fmul_rn(2.0f, g1v)), cs1));
      float qs1 = qsqS[16 + row];
      float h0v = __fadd_rn(__fadd_rn(c10h[rr], c10l[rr]), c10x[rr]);
      float h1v = __fadd_rn(__fadd_rn(c11h[rr], c11l[rr]), c11x[rr]);
      dkS[16 + row][g0 * 16 + colL] =
          ford(__fadd_rn(__fsub_rn(qs1, __fmul_rn(2.0f, h0v)), cs0));
      dkS[16 + row][g1 * 16 + colL] =
          ford(__fadd_rn(__fsub_rn(qs1, __fmul_rn(2.0f, h1v)), cs1));
    }
  }
  if (g < wend) {                       // odd tail: single group (w==0 only)
    int g0 = g;
    f32x4 z = {0.f, 0.f, 0.f, 0.f};
    f32x4 c00h = z, c00l = z, c00x = z;
    f32x4 c10h = z, c10l = z, c10x = z;
    #pragma unroll
    for (int ks = 0; ks < 6; ks++) {
      short8 b0h = fH[((size_t)ks * 64 + g0) * 64 + lane];
      short8 b0l = fL[((size_t)ks * 64 + g0) * 64 + lane];
      c00h = __builtin_amdgcn_mfma_f32_16x16x32_bf16(aH0[ks], b0h, c00h, 0, 0, 0);
      c00l = __builtin_amdgcn_mfma_f32_16x16x32_bf16(aH0[ks], b0l, c00l, 0, 0, 0);
      c00x = __builtin_amdgcn_mfma_f32_16x16x32_bf16(aL0[ks], b0h, c00x, 0, 0, 0);
      c10h = __builtin_amdgcn_mfma_f32_16x16x32_bf16(aH1[ks], b0h, c10h, 0, 0, 0);
      c10l = __builtin_amdgcn_mfma_f32_16x16x32_bf16(aH1[ks], b0l, c10l, 0, 0, 0);
      c10x = __builtin_amdgcn_mfma_f32_16x16x32_bf16(aL1[ks], b0h, c10x, 0, 0, 0);
    }
    float cs0 = sqb[g0 * 16 + colL];
    #pragma unroll
    for (int rr = 0; rr < 4; rr++) {
      int row = rq * 4 + rr;
      float qs0 = qsqS[row];
      float g0v = __fadd_rn(__fadd_rn(c00h[rr], c00l[rr]), c00x[rr]);
      dkS[row][g0 * 16 + colL] =
          ford(__fadd_rn(__fsub_rn(qs0, __fmul_rn(2.0f, g0v)), cs0));
      float qs1 = qsqS[16 + row];
      float h0v = __fadd_rn(__fadd_rn(c10h[rr], c10l[rr]), c10x[rr]);
      dkS[16 + row][g0 * 16 + colL] =
          ford(__fadd_rn(__fsub_rn(qs1, __fmul_rn(2.0f, h0v)), cs0));
    }
  }
  __syncthreads();

  // selection: wave w handles rows w*4 .. w*4+3 (13-strip scan, proven)
  for (int s = 0; s < 4; s++) {
    int row = w * 4 + s;
    if (q0 + row >= N_) continue;       // qt=24 phantom rows 16..31
    unsigned int bv = 0xFFFFFFFFu; int bi = lane;
    #pragma unroll
    for (int it = 0; it < 13; it++) {
      unsigned int k = dkS[row][lane + 64 * it];
      if (k < bv) { bv = k; bi = lane + 64 * it; }
    }
    int* o = nn9 + ((size_t)b * N_ + q0 + row) * K_;
    for (int kk = 0; kk < K_; kk++) {
      unsigned long long mk = ((unsigned long long)bv << 10) | (unsigned int)bi;
      #pragma unroll
      for (int off = 1; off < 64; off <<= 1) {
        unsigned long long v2 = __shfl_xor(mk, off);
        mk = v2 < mk ? v2 : mk;
      }
      int widx = (int)(mk & 1023u);
      if (lane == 0) o[kk] = widx;
      if ((widx & 63) == lane) {
        dkS[row][widx] = 0xFFFFFFFFu;
        bv = 0xFFFFFFFFu; bi = lane;
        #pragma unroll
        for (int it = 0; it < 13; it++) {
          unsigned int k = dkS[row][lane + 64 * it];
          if (k < bv) { bv = k; bi = lane + 64 * it; }
        }
      }
    }
  }
}

// ---------------------------------------------------------------------------
// K3: FUSED gather + max-rel + grouped conv, both halves per block (R15/17).
// ---------------------------------------------------------------------------
__global__ __launch_bounds__(256) void fconv_kernel(
    const float* __restrict__ x, const int* __restrict__ nn9,
    const float* __restrict__ w, const float* __restrict__ bias,
    float* __restrict__ outpre, float* __restrict__ psum,
    float* __restrict__ pss) {
  int nt = blockIdx.x;
  int g  = blockIdx.y;
  int b  = blockIdx.z;
  int n0 = nt * 112;
  int t = threadIdx.x;

  __shared__ float Wl[48][97];
  __shared__ float Hl[96][112];
  __shared__ unsigned short Il[112][K_];

  const int* isrc = nn9 + ((size_t)b * N_ + n0) * K_;
  for (int i = t; i < 112 * K_; i += 256)
    Il[i / K_][i % K_] = (unsigned short)isrc[i];
  const float* wsrc0 = w + (size_t)(g * 96) * 96;
  for (int i = t; i < 48 * 96; i += 256) Wl[i / 96][i % 96] = wsrc0[i];
  __syncthreads();

  const float* xb = x + (size_t)b * C_ * N_;
  for (int pos = t; pos < 48 * 112; pos += 256) {
    int cl = pos / 112, nl = pos % 112;
    const float* row = xb + (size_t)(g * 48 + cl) * N_;
    float xv = row[n0 + nl];
    float mx = -1e30f;
    #pragma unroll
    for (int k = 0; k < K_; k++) mx = fmaxf(mx, row[Il[nl][k]]);
    Hl[2 * cl][nl]     = xv;
    Hl[2 * cl + 1][nl] = mx - xv;
  }
  __syncthreads();

  int tx = t & 15, ty = t >> 4;
  int tidx = b * 7 + nt;

  for (int half = 0; half < 2; half++) {
    float o[3][7];
    #pragma unroll
    for (int i = 0; i < 3; i++)
      #pragma unroll
      for (int j = 0; j < 7; j++) o[i][j] = 0.f;

    for (int k = 0; k < 96; k++) {
      float w0 = Wl[ty * 3 + 0][k];
      float w1 = Wl[ty * 3 + 1][k];
      float w2 = Wl[ty * 3 + 2][k];
      #pragma unroll
      for (int j = 0; j < 7; j++) {
        float hv = Hl[k][tx * 7 + j];
        o[0][j] = __fmaf_rn(w0, hv, o[0][j]);
        o[1][j] = __fmaf_rn(w1, hv, o[1][j]);
        o[2][j] = __fmaf_rn(w2, hv, o[2][j]);
      }
    }

    #pragma unroll
    for (int i = 0; i < 3; i++) {
      int co = g * 96 + half * 48 + ty * 3 + i;
      float bv = bias[co];
      float s = 0.f, s2 = 0.f;
      float* orow = outpre + ((size_t)b * COUT_ + co) * N_ + n0 + tx * 7;
      #pragma unroll
      for (int j = 0; j < 7; j++) {
        float v = o[i][j] + bv;
        orow[j] = v;
        s += v; s2 += v * v;
      }
      #pragma unroll
      for (int off = 1; off < 16; off <<= 1) {
        s  += __shfl_xor(s, off);
        s2 += __shfl_xor(s2, off);
      }
      if (tx == 0) {
        psum[co * NTILES_ + tidx] = s;
        pss [co * NTILES_ + tidx] = s2;
      }
    }

    if (half == 0) {
      __syncthreads();
      const float* wsrc1 = w + (size_t)(g * 96 + 48) * 96;
      for (int i = t; i < 48 * 96; i += 256) Wl[i / 96][i % 96] = wsrc1[i];
      __syncthreads();
    }
  }
}

// ---------------------------------------------------------------------------
// K4: finalize BN stats -> per-channel affine a, b
// ---------------------------------------------------------------------------
__global__ __launch_bounds__(64) void stats_kernel(
    const float* __restrict__ psum, const float* __restrict__ pss,
    const float* __restrict__ gamma, const float* __restrict__ beta,
    float* __restrict__ af, float* __restrict__ bf) {
  int co = blockIdx.x;
  int l = threadIdx.x;
  double s = 0.0, s2 = 0.0;
  for (int i = l; i < NTILES_; i += 64) {
    s  += (double)psum[co * NTILES_ + i];
    s2 += (double)pss [co * NTILES_ + i];
  }
  #pragma unroll
  for (int o = 32; o > 0; o >>= 1) { s += __shfl_xor(s, o); s2 += __shfl_xor(s2, o); }
  if (l == 0) {
    const double cnt = (double)NPTS_;
    double mean = s / cnt;
    double var  = s2 / cnt - mean * mean;
    double rstd = 1.0 / sqrt(var + 1e-5);
    double a = (double)gamma[co] * rstd;
    af[co] = (float)a;
    bf[co] = (float)((double)beta[co] - mean * a);
  }
}

// ---------------------------------------------------------------------------
// K5: BN affine + exact GELU + fp32 store
// ---------------------------------------------------------------------------
__global__ __launch_bounds__(256) void act_kernel(
    const float* __restrict__ outpre, const float* __restrict__ af,
    const float* __restrict__ bf, float* __restrict__ out) {
  size_t i = ((size_t)blockIdx.x * 256 + threadIdx.x) * 4;
  int co = (int)((i / N_) % COUT_);
  float a = af[co], c = bf[co];
  float4 v = *(const float4*)(outpre + i);
  float y0 = a * v.x + c, y1 = a * v.y + c, y2 = a * v.z + c, y3 = a * v.w + c;
  const float is2 = 0.70710678118654752f;
  float4 r;
  r.x = 0.5f * y0 * (1.0f + erff(y0 * is2));
  r.y = 0.5f * y1 * (1.0f + erff(y1 * is2));
  r.z = 0.5f * y2 * (1.0f + erff(y2 * is2));
  r.w = 0.5f * y3 * (1.0f + erff(y3 * is2));
  *reinterpret_cast<float4*>(out + i) = r;
}

// ---------------------------------------------------------------------------
extern "C" void kernel_launch(void* const* d_in, const int* in_sizes, int n_in,
                              void* d_out, int out_size, void* d_ws, size_t ws_size,
                              hipStream_t stream) {
  const float* x      = (const float*)d_in[0];
  const float* conv_w = (const float*)d_in[1];
  const float* conv_b = (const float*)d_in[2];
  const float* gamma  = (const float*)d_in[3];
  const float* beta   = (const float*)d_in[4];
  float* out = (float*)d_out;

  // ws layout (float offsets), ~65 MB:
  float* buf0 = (float*)d_ws;
  short8* fragH = (short8*)buf0;                         // [0, 3145728)
  short8* fragL = (short8*)(buf0 + 3145728);             // [3145728, 6291456)
  float*  sqp   = buf0 + 6291456;                        // [6291456, 6324224)
  int*    nn9   = (int*)(buf0 + 6324224);                // [6324224, 6550016)
  float*  outpre = buf0 + 6550016;                       // [6550016, 16183808)
  float*  psum  = buf0 + 16183808;
  float*  pss   = psum + COUT_ * NTILES_;
  float*  af    = pss + COUT_ * NTILES_;
  float*  bfv   = af + COUT_;

  hipLaunchKernelGGL(norm_kernel, dim3(NPTS_ / 64), dim3(256), 0, stream,
                     x, fragH, fragL, sqp);
  hipLaunchKernelGGL(knn_kernel, dim3(25 * B_), dim3(512), 0, stream,
                     fragH, fragL, sqp, nn9);
  hipLaunchKernelGGL(fconv_kernel, dim3(7, 4, B_), dim3(256), 0, stream,
                     x, nn9, conv_w, conv_b, outpre, psum, pss);
  hipLaunchKernelGGL(stats_kernel, dim3(COUT_), dim3(64), 0, stream,
                     psum, pss, gamma, beta, af, bfv);
  hipLaunchKernelGGL(act_kernel, dim3((B_ * COUT_ * N_) / (256 * 4)), dim3(256), 0, stream,
                     outpre, af, bfv, out);
}

// Round 21
// 210.025 us; speedup vs baseline: 1.0810x; 1.0810x over previous
//
#include <hip/hip_runtime.h>

#define B_    32
#define C_    192
#define N_    784
#define NP_   1024        // sqp row stride (pad never read)
#define K_    9
#define COUT_ 384
#define NPTS_ (B_ * N_)   // 25088
#define NTILES_ 224       // 32 b * 7 ntiles
#define DKW_  836         // dkS row stride (>= 13*64=832)

typedef __attribute__((ext_vector_type(8))) short short8;   // 8 bf16 = 4 VGPR
typedef __attribute__((ext_vector_type(4))) float f32x4;    // MFMA acc

// ordered-uint transform: monotone map float -> uint
__device__ __forceinline__ unsigned int ford(float f) {
  unsigned int u = __float_as_uint(f);
  return u ^ ((u & 0x80000000u) ? 0xFFFFFFFFu : 0x80000000u);
}
// fp32 -> bf16 (RNE)
__device__ __forceinline__ unsigned short f2bf(float f) {
  unsigned int u = __float_as_uint(f);
  u += 0x7FFFu + ((u >> 16) & 1u);
  return (unsigned short)(u >> 16);
}
__device__ __forceinline__ float bf2f(unsigned short h) {
  return __uint_as_float(((unsigned int)h) << 16);
}

// ---------------------------------------------------------------------------
// K1: norm + FUSED frag pack (proven R17). Block = 64 pts x 4 c-groups.
// ---------------------------------------------------------------------------
__global__ __launch_bounds__(256) void norm_kernel(
    const float* __restrict__ x, short8* __restrict__ fragH,
    short8* __restrict__ fragL, float* __restrict__ sqp) {
  int t = threadIdx.x;
  int pl = t & 63, cg = t >> 6;
  int p = blockIdx.x * 64 + pl;
  int b = p / N_, n = p % N_;
  const float* xb = x + (size_t)b * C_ * N_ + n;

  __shared__ float red[4][64];
  __shared__ float nrmS[64];

  float part = 0.f;
  #pragma unroll 8
  for (int j = 0; j < 48; j++) {
    float v = xb[(size_t)(cg * 48 + j) * N_];
    part = __fmaf_rn(v, v, part);
  }
  red[cg][pl] = part;
  __syncthreads();
  if (t < 64) {
    float ssq = __fadd_rn(__fadd_rn(red[0][t], red[1][t]),
                          __fadd_rn(red[2][t], red[3][t]));
    nrmS[t] = fmaxf(__fsqrt_rn(ssq), 1e-12f);
  }
  __syncthreads();
  float nrm = nrmS[pl];
  int g = n >> 4, li = n & 15;
  float p2 = 0.f;
  #pragma unroll
  for (int s = 0; s < 6; s++) {
    int kslot = cg * 6 + s;          // 0..23
    int ks = kslot >> 2, kq = kslot & 3;
    union { short8 v; unsigned short u[8]; } ph, plo;
    #pragma unroll
    for (int j = 0; j < 8; j++) {
      float a = __fdiv_rn(xb[(size_t)(kslot * 8 + j) * N_], nrm);
      unsigned short h = f2bf(a);
      ph.u[j]  = h;
      plo.u[j] = f2bf(__fsub_rn(a, bf2f(h)));
      p2 = __fmaf_rn(a, a, p2);
    }
    size_t idx = (((size_t)b * 6 + ks) * 64 + g) * 64 + (kq * 16 + li);
    fragH[idx] = ph.v;
    fragL[idx] = plo.v;
  }
  red[cg][pl] = p2;
  __syncthreads();
  if (t < 64) {
    float sq = __fadd_rn(__fadd_rn(red[0][t], red[1][t]),
                         __fadd_rn(red[2][t], red[3][t]));
    int pp = blockIdx.x * 64 + t;
    sqp[(size_t)(pp / N_) * NP_ + (pp % N_)] = sq;
  }
}

// ---------------------------------------------------------------------------
// K2: MFMA KNN — R19 structure (proven 103.5 us) with LOAD-HOISTED pair
//  body: all 24 B-fragments of a pair loaded into named registers before
//  the 36 MFMAs (forces 24-deep MLP per wave). Distance chains and
//  selection bit-identical to R19.
// ---------------------------------------------------------------------------
__global__ __launch_bounds__(256) void knn_kernel(
    const short8* __restrict__ fragH, const short8* __restrict__ fragL,
    const float* __restrict__ sqp, int* __restrict__ nn9) {
  int wg = blockIdx.x;
  int r = wg & 7, j = wg >> 3;
  int b  = r + 8 * (j / 49);
  int qt = j % 49;
  int q0 = qt * 16;
  int t = threadIdx.x, lane = t & 63, w = t >> 6;

  __shared__ unsigned int dkS[16][DKW_];  // 53.5 KB keys
  __shared__ float qsqS[16];

  // preset pad cols [784, 836) to MAX (scanned strips cover up to 831)
  for (int i = t; i < 16 * 52; i += 256)
    dkS[i / 52][784 + i % 52] = 0xFFFFFFFFu;
  if (t < 16) qsqS[t] = sqp[(size_t)b * NP_ + q0 + t];
  __syncthreads();

  const float* sqb = sqp + (size_t)b * NP_;
  const short8* fH = fragH + (size_t)b * 6 * 64 * 64;
  const short8* fL = fragL + (size_t)b * 6 * 64 * 64;

  short8 aH[6], aL[6];
  #pragma unroll
  for (int ks = 0; ks < 6; ks++) {
    aH[ks] = fH[((size_t)ks * 64 + qt) * 64 + lane];
    aL[ks] = fL[((size_t)ks * 64 + qt) * 64 + lane];
  }

  int colL = lane & 15, rq = lane >> 4;
  const int wstart = (w == 0) ? 0 : (w == 1) ? 13 : (w == 2) ? 26 : 39;
  const int wend   = (w == 0) ? 13 : (w == 1) ? 26 : (w == 2) ? 39 : 49;

  int g = wstart;
  for (; g + 1 < wend; g += 2) {
    int g0 = g, g1 = g + 1;
    // ---- hoisted loads: 24 independent dwordx4 in flight ----
    short8 B0h[6], B0l[6], B1h[6], B1l[6];
    #pragma unroll
    for (int ks = 0; ks < 6; ks++) {
      B0h[ks] = fH[((size_t)ks * 64 + g0) * 64 + lane];
      B0l[ks] = fL[((size_t)ks * 64 + g0) * 64 + lane];
      B1h[ks] = fH[((size_t)ks * 64 + g1) * 64 + lane];
      B1l[ks] = fL[((size_t)ks * 64 + g1) * 64 + lane];
    }
    float cs0 = sqb[g0 * 16 + colL];
    float cs1 = sqb[g1 * 16 + colL];
    f32x4 a00 = {0.f, 0.f, 0.f, 0.f}, a01 = a00, a02 = a00;
    f32x4 a10 = a00, a11 = a00, a12 = a00;
    #pragma unroll
    for (int ks = 0; ks < 6; ks++) {
      a00 = __builtin_amdgcn_mfma_f32_16x16x32_bf16(aH[ks], B0h[ks], a00, 0, 0, 0);
      a01 = __builtin_amdgcn_mfma_f32_16x16x32_bf16(aH[ks], B0l[ks], a01, 0, 0, 0);
      a02 = __builtin_amdgcn_mfma_f32_16x16x32_bf16(aL[ks], B0h[ks], a02, 0, 0, 0);
      a10 = __builtin_amdgcn_mfma_f32_16x16x32_bf16(aH[ks], B1h[ks], a10, 0, 0, 0);
      a11 = __builtin_amdgcn_mfma_f32_16x16x32_bf16(aH[ks], B1l[ks], a11, 0, 0, 0);
      a12 = __builtin_amdgcn_mfma_f32_16x16x32_bf16(aL[ks], B1h[ks], a12, 0, 0, 0);
    }
    #pragma unroll
    for (int rr = 0; rr < 4; rr++) {
      int row = rq * 4 + rr;
      float qs = qsqS[row];
      float g0v = __fadd_rn(__fadd_rn(a00[rr], a01[rr]), a02[rr]);
      float g1v = __fadd_rn(__fadd_rn(a10[rr], a11[rr]), a12[rr]);
      float d0 = __fadd_rn(__fsub_rn(qs, __fmul_rn(2.0f, g0v)), cs0);
      float d1 = __fadd_rn(__fsub_rn(qs, __fmul_rn(2.0f, g1v)), cs1);
      dkS[row][g0 * 16 + colL] = ford(d0);
      dkS[row][g1 * 16 + colL] = ford(d1);
    }
  }
  if (g < wend) {                       // odd tail: single group
    int g0 = g;
    short8 B0h[6], B0l[6];
    #pragma unroll
    for (int ks = 0; ks < 6; ks++) {
      B0h[ks] = fH[((size_t)ks * 64 + g0) * 64 + lane];
      B0l[ks] = fL[((size_t)ks * 64 + g0) * 64 + lane];
    }
    float cs0 = sqb[g0 * 16 + colL];
    f32x4 a00 = {0.f, 0.f, 0.f, 0.f}, a01 = a00, a02 = a00;
    #pragma unroll
    for (int ks = 0; ks < 6; ks++) {
      a00 = __builtin_amdgcn_mfma_f32_16x16x32_bf16(aH[ks], B0h[ks], a00, 0, 0, 0);
      a01 = __builtin_amdgcn_mfma_f32_16x16x32_bf16(aH[ks], B0l[ks], a01, 0, 0, 0);
      a02 = __builtin_amdgcn_mfma_f32_16x16x32_bf16(aL[ks], B0h[ks], a02, 0, 0, 0);
    }
    #pragma unroll
    for (int rr = 0; rr < 4; rr++) {
      int row = rq * 4 + rr;
      float qs = qsqS[row];
      float g0v = __fadd_rn(__fadd_rn(a00[rr], a01[rr]), a02[rr]);
      float d0 = __fadd_rn(__fsub_rn(qs, __fmul_rn(2.0f, g0v)), cs0);
      dkS[row][g0 * 16 + colL] = ford(d0);
    }
  }
  __syncthreads();

  for (int s = 0; s < 4; s++) {
    int row = w * 4 + s;
    unsigned int bv = 0xFFFFFFFFu; int bi = lane;
    #pragma unroll
    for (int it = 0; it < 13; it++) {
      unsigned int k = dkS[row][lane + 64 * it];
      if (k < bv) { bv = k; bi = lane + 64 * it; }
    }
    int* o = nn9 + ((size_t)b * N_ + q0 + row) * K_;
    for (int kk = 0; kk < K_; kk++) {
      unsigned long long mk = ((unsigned long long)bv << 10) | (unsigned int)bi;
      #pragma unroll
      for (int off = 1; off < 64; off <<= 1) {
        unsigned long long v2 = __shfl_xor(mk, off);
        mk = v2 < mk ? v2 : mk;
      }
      int widx = (int)(mk & 1023u);
      if (lane == 0) o[kk] = widx;
      if ((widx & 63) == lane) {
        dkS[row][widx] = 0xFFFFFFFFu;
        bv = 0xFFFFFFFFu; bi = lane;
        #pragma unroll
        for (int it = 0; it < 13; it++) {
          unsigned int k = dkS[row][lane + 64 * it];
          if (k < bv) { bv = k; bi = lane + 64 * it; }
        }
      }
    }
  }
}

// ---------------------------------------------------------------------------
// K3: FUSED gather + max-rel + grouped conv, both halves per block (R15/17).
// ---------------------------------------------------------------------------
__global__ __launch_bounds__(256) void fconv_kernel(
    const float* __restrict__ x, const int* __restrict__ nn9,
    const float* __restrict__ w, const float* __restrict__ bias,
    float* __restrict__ outpre, float* __restrict__ psum,
    float* __restrict__ pss) {
  int nt = blockIdx.x;
  int g  = blockIdx.y;
  int b  = blockIdx.z;
  int n0 = nt * 112;
  int t = threadIdx.x;

  __shared__ float Wl[48][97];
  __shared__ float Hl[96][112];
  __shared__ unsigned short Il[112][K_];

  const int* isrc = nn9 + ((size_t)b * N_ + n0) * K_;
  for (int i = t; i < 112 * K_; i += 256)
    Il[i / K_][i % K_] = (unsigned short)isrc[i];
  const float* wsrc0 = w + (size_t)(g * 96) * 96;
  for (int i = t; i < 48 * 96; i += 256) Wl[i / 96][i % 96] = wsrc0[i];
  __syncthreads();

  const float* xb = x + (size_t)b * C_ * N_;
  for (int pos = t; pos < 48 * 112; pos += 256) {
    int cl = pos / 112, nl = pos % 112;
    const float* row = xb + (size_t)(g * 48 + cl) * N_;
    float xv = row[n0 + nl];
    float mx = -1e30f;
    #pragma unroll
    for (int k = 0; k < K_; k++) mx = fmaxf(mx, row[Il[nl][k]]);
    Hl[2 * cl][nl]     = xv;
    Hl[2 * cl + 1][nl] = mx - xv;
  }
  __syncthreads();

  int tx = t & 15, ty = t >> 4;
  int tidx = b * 7 + nt;

  for (int half = 0; half < 2; half++) {
    float o[3][7];
    #pragma unroll
    for (int i = 0; i < 3; i++)
      #pragma unroll
      for (int j = 0; j < 7; j++) o[i][j] = 0.f;

    for (int k = 0; k < 96; k++) {
      float w0 = Wl[ty * 3 + 0][k];
      float w1 = Wl[ty * 3 + 1][k];
      float w2 = Wl[ty * 3 + 2][k];
      #pragma unroll
      for (int j = 0; j < 7; j++) {
        float hv = Hl[k][tx * 7 + j];
        o[0][j] = __fmaf_rn(w0, hv, o[0][j]);
        o[1][j] = __fmaf_rn(w1, hv, o[1][j]);
        o[2][j] = __fmaf_rn(w2, hv, o[2][j]);
      }
    }

    #pragma unroll
    for (int i = 0; i < 3; i++) {
      int co = g * 96 + half * 48 + ty * 3 + i;
      float bv = bias[co];
      float s = 0.f, s2 = 0.f;
      float* orow = outpre + ((size_t)b * COUT_ + co) * N_ + n0 + tx * 7;
      #pragma unroll
      for (int j = 0; j < 7; j++) {
        float v = o[i][j] + bv;
        orow[j] = v;
        s += v; s2 += v * v;
      }
      #pragma unroll
      for (int off = 1; off < 16; off <<= 1) {
        s  += __shfl_xor(s, off);
        s2 += __shfl_xor(s2, off);
      }
      if (tx == 0) {
        psum[co * NTILES_ + tidx] = s;
        pss [co * NTILES_ + tidx] = s2;
      }
    }

    if (half == 0) {
      __syncthreads();
      const float* wsrc1 = w + (size_t)(g * 96 + 48) * 96;
      for (int i = t; i < 48 * 96; i += 256) Wl[i / 96][i % 96] = wsrc1[i];
      __syncthreads();
    }
  }
}

// ---------------------------------------------------------------------------
// K4: finalize BN stats -> per-channel affine a, b
// ---------------------------------------------------------------------------
__global__ __launch_bounds__(64) void stats_kernel(
    const float* __restrict__ psum, const float* __restrict__ pss,
    const float* __restrict__ gamma, const float* __restrict__ beta,
    float* __restrict__ af, float* __restrict__ bf) {
  int co = blockIdx.x;
  int l = threadIdx.x;
  double s = 0.0, s2 = 0.0;
  for (int i = l; i < NTILES_; i += 64) {
    s  += (double)psum[co * NTILES_ + i];
    s2 += (double)pss [co * NTILES_ + i];
  }
  #pragma unroll
  for (int o = 32; o > 0; o >>= 1) { s += __shfl_xor(s, o); s2 += __shfl_xor(s2, o); }
  if (l == 0) {
    const double cnt = (double)NPTS_;
    double mean = s / cnt;
    double var  = s2 / cnt - mean * mean;
    double rstd = 1.0 / sqrt(var + 1e-5);
    double a = (double)gamma[co] * rstd;
    af[co] = (float)a;
    bf[co] = (float)((double)beta[co] - mean * a);
  }
}

// ---------------------------------------------------------------------------
// K5: BN affine + exact GELU + fp32 store
// ---------------------------------------------------------------------------
__global__ __launch_bounds__(256) void act_kernel(
    const float* __restrict__ outpre, const float* __restrict__ af,
    const float* __restrict__ bf, float* __restrict__ out) {
  size_t i = ((size_t)blockIdx.x * 256 + threadIdx.x) * 4;
  int co = (int)((i / N_) % COUT_);
  float a = af[co], c = bf[co];
  float4 v = *(const float4*)(outpre + i);
  float y0 = a * v.x + c, y1 = a * v.y + c, y2 = a * v.z + c, y3 = a * v.w + c;
  const float is2 = 0.70710678118654752f;
  float4 r;
  r.x = 0.5f * y0 * (1.0f + erff(y0 * is2));
  r.y = 0.5f * y1 * (1.0f + erff(y1 * is2));
  r.z = 0.5f * y2 * (1.0f + erff(y2 * is2));
  r.w = 0.5f * y3 * (1.0f + erff(y3 * is2));
  *reinterpret_cast<float4*>(out + i) = r;
}

// ---------------------------------------------------------------------------
extern "C" void kernel_launch(void* const* d_in, const int* in_sizes, int n_in,
                              void* d_out, int out_size, void* d_ws, size_t ws_size,
                              hipStream_t stream) {
  const float* x      = (const float*)d_in[0];
  const float* conv_w = (const float*)d_in[1];
  const float* conv_b = (const float*)d_in[2];
  const float* gamma  = (const float*)d_in[3];
  const float* beta   = (const float*)d_in[4];
  float* out = (float*)d_out;

  // ws layout (float offsets), ~65 MB:
  float* buf0 = (float*)d_ws;
  short8* fragH = (short8*)buf0;                         // [0, 3145728)
  short8* fragL = (short8*)(buf0 + 3145728);             // [3145728, 6291456)
  float*  sqp   = buf0 + 6291456;                        // [6291456, 6324224)
  int*    nn9   = (int*)(buf0 + 6324224);                // [6324224, 6550016)
  float*  outpre = buf0 + 6550016;                       // [6550016, 16183808)
  float*  psum  = buf0 + 16183808;
  float*  pss   = psum + COUT_ * NTILES_;
  float*  af    = pss + COUT_ * NTILES_;
  float*  bfv   = af + COUT_;

  hipLaunchKernelGGL(norm_kernel, dim3(NPTS_ / 64), dim3(256), 0, stream,
                     x, fragH, fragL, sqp);
  hipLaunchKernelGGL(knn_kernel, dim3(49 * B_), dim3(256), 0, stream,
                     fragH, fragL, sqp, nn9);
  hipLaunchKernelGGL(fconv_kernel, dim3(7, 4, B_), dim3(256), 0, stream,
                     x, nn9, conv_w, conv_b, outpre, psum, pss);
  hipLaunchKernelGGL(stats_kernel, dim3(COUT_), dim3(64), 0, stream,
                     psum, pss, gamma, beta, af, bfv);
  hipLaunchKernelGGL(act_kernel, dim3((B_ * COUT_ * N_) / (256 * 4)), dim3(256), 0, stream,
                     outpre, af, bfv, out);
}

// Round 22
// 200.469 us; speedup vs baseline: 1.1326x; 1.0477x over previous
//
#include <hip/hip_runtime.h>

#define B_    32
#define C_    192
#define N_    784
#define NP_   1024        // sqp row stride (pad never read)
#define K_    9
#define COUT_ 384
#define NPTS_ (B_ * N_)   // 25088
#define NTILES_ 224       // 32 b * 7 ntiles
#define DKW_  836         // dkS row stride (>= 13*64=832)

typedef __attribute__((ext_vector_type(8))) short short8;   // 8 bf16 = 4 VGPR
typedef __attribute__((ext_vector_type(4))) float f32x4;    // MFMA acc

// ordered-uint transform: monotone map float -> uint
__device__ __forceinline__ unsigned int ford(float f) {
  unsigned int u = __float_as_uint(f);
  return u ^ ((u & 0x80000000u) ? 0xFFFFFFFFu : 0x80000000u);
}
// fp32 -> bf16 (RNE)
__device__ __forceinline__ unsigned short f2bf(float f) {
  unsigned int u = __float_as_uint(f);
  u += 0x7FFFu + ((u >> 16) & 1u);
  return (unsigned short)(u >> 16);
}
__device__ __forceinline__ float bf2f(unsigned short h) {
  return __uint_as_float(((unsigned int)h) << 16);
}

// ---------------------------------------------------------------------------
// K1: norm + FUSED frag pack (proven R17) + xT transpose write.
// Block = 64 pts x 4 c-groups.
// ---------------------------------------------------------------------------
__global__ __launch_bounds__(256) void norm_kernel(
    const float* __restrict__ x, short8* __restrict__ fragH,
    short8* __restrict__ fragL, float* __restrict__ sqp,
    float* __restrict__ xT) {
  int t = threadIdx.x;
  int pl = t & 63, cg = t >> 6;
  int p = blockIdx.x * 64 + pl;
  int b = p / N_, n = p % N_;
  const float* xb = x + (size_t)b * C_ * N_ + n;
  float* xTp = xT + (size_t)p * C_ + cg * 48;

  __shared__ float red[4][64];
  __shared__ float nrmS[64];

  float part = 0.f;
  #pragma unroll
  for (int j = 0; j < 48; j++) {
    float v = xb[(size_t)(cg * 48 + j) * N_];
    xTp[j] = v;                       // transposed copy (contiguous 48)
    part = __fmaf_rn(v, v, part);
  }
  red[cg][pl] = part;
  __syncthreads();
  if (t < 64) {
    float ssq = __fadd_rn(__fadd_rn(red[0][t], red[1][t]),
                          __fadd_rn(red[2][t], red[3][t]));
    nrmS[t] = fmaxf(__fsqrt_rn(ssq), 1e-12f);
  }
  __syncthreads();
  float nrm = nrmS[pl];
  int g = n >> 4, li = n & 15;
  float p2 = 0.f;
  #pragma unroll
  for (int s = 0; s < 6; s++) {
    int kslot = cg * 6 + s;          // 0..23
    int ks = kslot >> 2, kq = kslot & 3;
    union { short8 v; unsigned short u[8]; } ph, plo;
    #pragma unroll
    for (int j = 0; j < 8; j++) {
      float a = __fdiv_rn(xb[(size_t)(kslot * 8 + j) * N_], nrm);
      unsigned short h = f2bf(a);
      ph.u[j]  = h;
      plo.u[j] = f2bf(__fsub_rn(a, bf2f(h)));
      p2 = __fmaf_rn(a, a, p2);
    }
    size_t idx = (((size_t)b * 6 + ks) * 64 + g) * 64 + (kq * 16 + li);
    fragH[idx] = ph.v;
    fragL[idx] = plo.v;
  }
  red[cg][pl] = p2;
  __syncthreads();
  if (t < 64) {
    float sq = __fadd_rn(__fadd_rn(red[0][t], red[1][t]),
                         __fadd_rn(red[2][t], red[3][t]));
    int pp = blockIdx.x * 64 + t;
    sqp[(size_t)(pp / N_) * NP_ + (pp % N_)] = sq;
  }
}

// ---------------------------------------------------------------------------
// K2: MFMA KNN — R19/R21 structure (proven 103.5 us), unchanged.
// ---------------------------------------------------------------------------
__global__ __launch_bounds__(256) void knn_kernel(
    const short8* __restrict__ fragH, const short8* __restrict__ fragL,
    const float* __restrict__ sqp, int* __restrict__ nn9) {
  int wg = blockIdx.x;
  int r = wg & 7, j = wg >> 3;
  int b  = r + 8 * (j / 49);
  int qt = j % 49;
  int q0 = qt * 16;
  int t = threadIdx.x, lane = t & 63, w = t >> 6;

  __shared__ unsigned int dkS[16][DKW_];  // 53.5 KB keys
  __shared__ float qsqS[16];

  for (int i = t; i < 16 * 52; i += 256)
    dkS[i / 52][784 + i % 52] = 0xFFFFFFFFu;
  if (t < 16) qsqS[t] = sqp[(size_t)b * NP_ + q0 + t];
  __syncthreads();

  const float* sqb = sqp + (size_t)b * NP_;
  const short8* fH = fragH + (size_t)b * 6 * 64 * 64;
  const short8* fL = fragL + (size_t)b * 6 * 64 * 64;

  short8 aH[6], aL[6];
  #pragma unroll
  for (int ks = 0; ks < 6; ks++) {
    aH[ks] = fH[((size_t)ks * 64 + qt) * 64 + lane];
    aL[ks] = fL[((size_t)ks * 64 + qt) * 64 + lane];
  }

  int colL = lane & 15, rq = lane >> 4;
  const int wstart = (w == 0) ? 0 : (w == 1) ? 13 : (w == 2) ? 26 : 39;
  const int wend   = (w == 0) ? 13 : (w == 1) ? 26 : (w == 2) ? 39 : 49;

  int g = wstart;
  for (; g + 1 < wend; g += 2) {
    int g0 = g, g1 = g + 1;
    short8 B0h[6], B0l[6], B1h[6], B1l[6];
    #pragma unroll
    for (int ks = 0; ks < 6; ks++) {
      B0h[ks] = fH[((size_t)ks * 64 + g0) * 64 + lane];
      B0l[ks] = fL[((size_t)ks * 64 + g0) * 64 + lane];
      B1h[ks] = fH[((size_t)ks * 64 + g1) * 64 + lane];
      B1l[ks] = fL[((size_t)ks * 64 + g1) * 64 + lane];
    }
    float cs0 = sqb[g0 * 16 + colL];
    float cs1 = sqb[g1 * 16 + colL];
    f32x4 a00 = {0.f, 0.f, 0.f, 0.f}, a01 = a00, a02 = a00;
    f32x4 a10 = a00, a11 = a00, a12 = a00;
    #pragma unroll
    for (int ks = 0; ks < 6; ks++) {
      a00 = __builtin_amdgcn_mfma_f32_16x16x32_bf16(aH[ks], B0h[ks], a00, 0, 0, 0);
      a01 = __builtin_amdgcn_mfma_f32_16x16x32_bf16(aH[ks], B0l[ks], a01, 0, 0, 0);
      a02 = __builtin_amdgcn_mfma_f32_16x16x32_bf16(aL[ks], B0h[ks], a02, 0, 0, 0);
      a10 = __builtin_amdgcn_mfma_f32_16x16x32_bf16(aH[ks], B1h[ks], a10, 0, 0, 0);
      a11 = __builtin_amdgcn_mfma_f32_16x16x32_bf16(aH[ks], B1l[ks], a11, 0, 0, 0);
      a12 = __builtin_amdgcn_mfma_f32_16x16x32_bf16(aL[ks], B1h[ks], a12, 0, 0, 0);
    }
    #pragma unroll
    for (int rr = 0; rr < 4; rr++) {
      int row = rq * 4 + rr;
      float qs = qsqS[row];
      float g0v = __fadd_rn(__fadd_rn(a00[rr], a01[rr]), a02[rr]);
      float g1v = __fadd_rn(__fadd_rn(a10[rr], a11[rr]), a12[rr]);
      float d0 = __fadd_rn(__fsub_rn(qs, __fmul_rn(2.0f, g0v)), cs0);
      float d1 = __fadd_rn(__fsub_rn(qs, __fmul_rn(2.0f, g1v)), cs1);
      dkS[row][g0 * 16 + colL] = ford(d0);
      dkS[row][g1 * 16 + colL] = ford(d1);
    }
  }
  if (g < wend) {                       // odd tail: single group
    int g0 = g;
    short8 B0h[6], B0l[6];
    #pragma unroll
    for (int ks = 0; ks < 6; ks++) {
      B0h[ks] = fH[((size_t)ks * 64 + g0) * 64 + lane];
      B0l[ks] = fL[((size_t)ks * 64 + g0) * 64 + lane];
    }
    float cs0 = sqb[g0 * 16 + colL];
    f32x4 a00 = {0.f, 0.f, 0.f, 0.f}, a01 = a00, a02 = a00;
    #pragma unroll
    for (int ks = 0; ks < 6; ks++) {
      a00 = __builtin_amdgcn_mfma_f32_16x16x32_bf16(aH[ks], B0h[ks], a00, 0, 0, 0);
      a01 = __builtin_amdgcn_mfma_f32_16x16x32_bf16(aH[ks], B0l[ks], a01, 0, 0, 0);
      a02 = __builtin_amdgcn_mfma_f32_16x16x32_bf16(aL[ks], B0h[ks], a02, 0, 0, 0);
    }
    #pragma unroll
    for (int rr = 0; rr < 4; rr++) {
      int row = rq * 4 + rr;
      float qs = qsqS[row];
      float g0v = __fadd_rn(__fadd_rn(a00[rr], a01[rr]), a02[rr]);
      float d0 = __fadd_rn(__fsub_rn(qs, __fmul_rn(2.0f, g0v)), cs0);
      dkS[row][g0 * 16 + colL] = ford(d0);
    }
  }
  __syncthreads();

  for (int s = 0; s < 4; s++) {
    int row = w * 4 + s;
    unsigned int bv = 0xFFFFFFFFu; int bi = lane;
    #pragma unroll
    for (int it = 0; it < 13; it++) {
      unsigned int k = dkS[row][lane + 64 * it];
      if (k < bv) { bv = k; bi = lane + 64 * it; }
    }
    int* o = nn9 + ((size_t)b * N_ + q0 + row) * K_;
    for (int kk = 0; kk < K_; kk++) {
      unsigned long long mk = ((unsigned long long)bv << 10) | (unsigned int)bi;
      #pragma unroll
      for (int off = 1; off < 64; off <<= 1) {
        unsigned long long v2 = __shfl_xor(mk, off);
        mk = v2 < mk ? v2 : mk;
      }
      int widx = (int)(mk & 1023u);
      if (lane == 0) o[kk] = widx;
      if ((widx & 63) == lane) {
        dkS[row][widx] = 0xFFFFFFFFu;
        bv = 0xFFFFFFFFu; bi = lane;
        #pragma unroll
        for (int it = 0; it < 13; it++) {
          unsigned int k = dkS[row][lane + 64 * it];
          if (k < bv) { bv = k; bi = lane + 64 * it; }
        }
      }
    }
  }
}

// ---------------------------------------------------------------------------
// K3: FUSED gather + max-rel + grouped conv — gather via TRANSPOSED xT
//  (contiguous float4 channel reads, ~4x fewer load issues). GEMM phase
//  and all value chains identical to proven R17 version.
// ---------------------------------------------------------------------------
__global__ __launch_bounds__(256) void fconv_kernel(
    const float* __restrict__ xT, const int* __restrict__ nn9,
    const float* __restrict__ w, const float* __restrict__ bias,
    float* __restrict__ outpre, float* __restrict__ psum,
    float* __restrict__ pss) {
  int nt = blockIdx.x;
  int g  = blockIdx.y;
  int b  = blockIdx.z;
  int n0 = nt * 112;
  int t = threadIdx.x;

  __shared__ float Wl[48][97];
  __shared__ float Hl[96][112];
  __shared__ unsigned short Il[112][K_];

  const int* isrc = nn9 + ((size_t)b * N_ + n0) * K_;
  for (int i = t; i < 112 * K_; i += 256)
    Il[i / K_][i % K_] = (unsigned short)isrc[i];
  const float* wsrc0 = w + (size_t)(g * 96) * 96;
  for (int i = t; i < 48 * 96; i += 256) Wl[i / 96][i % 96] = wsrc0[i];
  __syncthreads();

  // gather phase: thread (nl, half) handles 24 channels via float4 reads
  if (t < 224) {
    int nl = t >> 1, half = t & 1;
    const float* xrow = xT + ((size_t)b * N_ + n0 + nl) * C_ + g * 48 + half * 24;
    float xv[24], mx[24];
    #pragma unroll
    for (int j = 0; j < 24; j += 4) {
      float4 v = *(const float4*)(xrow + j);
      xv[j] = v.x; xv[j + 1] = v.y; xv[j + 2] = v.z; xv[j + 3] = v.w;
      mx[j] = -1e30f; mx[j + 1] = -1e30f; mx[j + 2] = -1e30f; mx[j + 3] = -1e30f;
    }
    #pragma unroll
    for (int k = 0; k < K_; k++) {
      int idx = Il[nl][k];
      const float* nrow = xT + ((size_t)b * N_ + idx) * C_ + g * 48 + half * 24;
      #pragma unroll
      for (int j = 0; j < 24; j += 4) {
        float4 v = *(const float4*)(nrow + j);
        mx[j]     = fmaxf(mx[j], v.x);
        mx[j + 1] = fmaxf(mx[j + 1], v.y);
        mx[j + 2] = fmaxf(mx[j + 2], v.z);
        mx[j + 3] = fmaxf(mx[j + 3], v.w);
      }
    }
    #pragma unroll
    for (int j = 0; j < 24; j++) {
      int cl = half * 24 + j;
      Hl[2 * cl][nl]     = xv[j];
      Hl[2 * cl + 1][nl] = mx[j] - xv[j];
    }
  }
  __syncthreads();

  int tx = t & 15, ty = t >> 4;
  int tidx = b * 7 + nt;

  for (int half = 0; half < 2; half++) {
    float o[3][7];
    #pragma unroll
    for (int i = 0; i < 3; i++)
      #pragma unroll
      for (int j = 0; j < 7; j++) o[i][j] = 0.f;

    for (int k = 0; k < 96; k++) {
      float w0 = Wl[ty * 3 + 0][k];
      float w1 = Wl[ty * 3 + 1][k];
      float w2 = Wl[ty * 3 + 2][k];
      #pragma unroll
      for (int j = 0; j < 7; j++) {
        float hv = Hl[k][tx * 7 + j];
        o[0][j] = __fmaf_rn(w0, hv, o[0][j]);
        o[1][j] = __fmaf_rn(w1, hv, o[1][j]);
        o[2][j] = __fmaf_rn(w2, hv, o[2][j]);
      }
    }

    #pragma unroll
    for (int i = 0; i < 3; i++) {
      int co = g * 96 + half * 48 + ty * 3 + i;
      float bv = bias[co];
      float s = 0.f, s2 = 0.f;
      float* orow = outpre + ((size_t)b * COUT_ + co) * N_ + n0 + tx * 7;
      #pragma unroll
      for (int j = 0; j < 7; j++) {
        float v = o[i][j] + bv;
        orow[j] = v;
        s += v; s2 += v * v;
      }
      #pragma unroll
      for (int off = 1; off < 16; off <<= 1) {
        s  += __shfl_xor(s, off);
        s2 += __shfl_xor(s2, off);
      }
      if (tx == 0) {
        psum[co * NTILES_ + tidx] = s;
        pss [co * NTILES_ + tidx] = s2;
      }
    }

    if (half == 0) {
      __syncthreads();
      const float* wsrc1 = w + (size_t)(g * 96 + 48) * 96;
      for (int i = t; i < 48 * 96; i += 256) Wl[i / 96][i % 96] = wsrc1[i];
      __syncthreads();
    }
  }
}

// ---------------------------------------------------------------------------
// K4: finalize BN stats -> per-channel affine a, b
// ---------------------------------------------------------------------------
__global__ __launch_bounds__(64) void stats_kernel(
    const float* __restrict__ psum, const float* __restrict__ pss,
    const float* __restrict__ gamma, const float* __restrict__ beta,
    float* __restrict__ af, float* __restrict__ bf) {
  int co = blockIdx.x;
  int l = threadIdx.x;
  double s = 0.0, s2 = 0.0;
  for (int i = l; i < NTILES_; i += 64) {
    s  += (double)psum[co * NTILES_ + i];
    s2 += (double)pss [co * NTILES_ + i];
  }
  #pragma unroll
  for (int o = 32; o > 0; o >>= 1) { s += __shfl_xor(s, o); s2 += __shfl_xor(s2, o); }
  if (l == 0) {
    const double cnt = (double)NPTS_;
    double mean = s / cnt;
    double var  = s2 / cnt - mean * mean;
    double rstd = 1.0 / sqrt(var + 1e-5);
    double a = (double)gamma[co] * rstd;
    af[co] = (float)a;
    bf[co] = (float)((double)beta[co] - mean * a);
  }
}

// ---------------------------------------------------------------------------
// K5: BN affine + exact GELU + fp32 store
// ---------------------------------------------------------------------------
__global__ __launch_bounds__(256) void act_kernel(
    const float* __restrict__ outpre, const float* __restrict__ af,
    const float* __restrict__ bf, float* __restrict__ out) {
  size_t i = ((size_t)blockIdx.x * 256 + threadIdx.x) * 4;
  int co = (int)((i / N_) % COUT_);
  float a = af[co], c = bf[co];
  float4 v = *(const float4*)(outpre + i);
  float y0 = a * v.x + c, y1 = a * v.y + c, y2 = a * v.z + c, y3 = a * v.w + c;
  const float is2 = 0.70710678118654752f;
  float4 r;
  r.x = 0.5f * y0 * (1.0f + erff(y0 * is2));
  r.y = 0.5f * y1 * (1.0f + erff(y1 * is2));
  r.z = 0.5f * y2 * (1.0f + erff(y2 * is2));
  r.w = 0.5f * y3 * (1.0f + erff(y3 * is2));
  *reinterpret_cast<float4*>(out + i) = r;
}

// ---------------------------------------------------------------------------
extern "C" void kernel_launch(void* const* d_in, const int* in_sizes, int n_in,
                              void* d_out, int out_size, void* d_ws, size_t ws_size,
                              hipStream_t stream) {
  const float* x      = (const float*)d_in[0];
  const float* conv_w = (const float*)d_in[1];
  const float* conv_b = (const float*)d_in[2];
  const float* gamma  = (const float*)d_in[3];
  const float* beta   = (const float*)d_in[4];
  float* out = (float*)d_out;

  // ws layout (float offsets), peak 59.5 MB:
  //  [0, 6291456)   frags (norm->knn)  /  outpre [0, 9633792) (fconv->act)
  //  [9633792, ...] sqp | nn9 | xT | psum | pss | af | bf
  float* buf0 = (float*)d_ws;
  short8* fragH = (short8*)buf0;                         // [0, 3145728)
  short8* fragL = (short8*)(buf0 + 3145728);             // [3145728, 6291456)
  float*  outpre = buf0;                                 // overlay (frags dead)
  float*  sqp   = buf0 + 9633792;                        // 32768
  int*    nn9   = (int*)(buf0 + 9666560);                // 225792
  float*  xT    = buf0 + 9892352;                        // 4816896
  float*  psum  = buf0 + 14709248;                       // 86016
  float*  pss   = psum + COUT_ * NTILES_;                // 86016
  float*  af    = pss + COUT_ * NTILES_;
  float*  bfv   = af + COUT_;

  hipLaunchKernelGGL(norm_kernel, dim3(NPTS_ / 64), dim3(256), 0, stream,
                     x, fragH, fragL, sqp, xT);
  hipLaunchKernelGGL(knn_kernel, dim3(49 * B_), dim3(256), 0, stream,
                     fragH, fragL, sqp, nn9);
  hipLaunchKernelGGL(fconv_kernel, dim3(7, 4, B_), dim3(256), 0, stream,
                     xT, nn9, conv_w, conv_b, outpre, psum, pss);
  hipLaunchKernelGGL(stats_kernel, dim3(COUT_), dim3(64), 0, stream,
                     psum, pss, gamma, beta, af, bfv);
  hipLaunchKernelGGL(act_kernel, dim3((B_ * COUT_ * N_) / (256 * 4)), dim3(256), 0, stream,
                     outpre, af, bfv, out);
}

// Round 23
// 192.370 us; speedup vs baseline: 1.1802x; 1.0421x over previous
//
#include <hip/hip_runtime.h>

#define B_    32
#define C_    192
#define N_    784
#define NP_   1024        // sqp row stride (pad never read)
#define K_    9
#define COUT_ 384
#define NPTS_ (B_ * N_)   // 25088
#define NTILES_ 224       // 32 b * 7 ntiles
#define DKW_  836         // dkS row stride (>= 13*64=832)

typedef __attribute__((ext_vector_type(8))) short short8;   // 8 bf16 = 4 VGPR
typedef __attribute__((ext_vector_type(4))) float f32x4;    // MFMA acc

// ordered-uint transform: monotone map float -> uint
__device__ __forceinline__ unsigned int ford(float f) {
  unsigned int u = __float_as_uint(f);
  return u ^ ((u & 0x80000000u) ? 0xFFFFFFFFu : 0x80000000u);
}
// fp32 -> bf16 (RNE)
__device__ __forceinline__ unsigned short f2bf(float f) {
  unsigned int u = __float_as_uint(f);
  u += 0x7FFFu + ((u >> 16) & 1u);
  return (unsigned short)(u >> 16);
}
__device__ __forceinline__ float bf2f(unsigned short h) {
  return __uint_as_float(((unsigned int)h) << 16);
}

// ---------------------------------------------------------------------------
// K1: norm + frag pack + COALESCED xT via LDS transpose.
//  Single global read of x (staged in Tl); pack + sums read LDS.
//  All value chains bit-identical to R22 (same floats, different path).
// ---------------------------------------------------------------------------
__global__ __launch_bounds__(256) void norm_kernel(
    const float* __restrict__ x, short8* __restrict__ fragH,
    short8* __restrict__ fragL, float* __restrict__ sqp,
    float* __restrict__ xT) {
  int t = threadIdx.x;
  int pl = t & 63, cg = t >> 6;
  int p = blockIdx.x * 64 + pl;
  int b = p / N_, n = p % N_;
  const float* xb = x + (size_t)b * C_ * N_ + n;

  __shared__ float Tl[64][193];   // 49.4 KB
  __shared__ float red[4][64];
  __shared__ float nrmS[64];

  float part = 0.f;
  #pragma unroll
  for (int j = 0; j < 48; j++) {
    float v = xb[(size_t)(cg * 48 + j) * N_];
    Tl[pl][cg * 48 + j] = v;
    part = __fmaf_rn(v, v, part);
  }
  red[cg][pl] = part;
  __syncthreads();
  if (t < 64) {
    float ssq = __fadd_rn(__fadd_rn(red[0][t], red[1][t]),
                          __fadd_rn(red[2][t], red[3][t]));
    nrmS[t] = fmaxf(__fsqrt_rn(ssq), 1e-12f);
  }
  __syncthreads();

  // coalesced xT write: consecutive t -> consecutive c within point row
  {
    size_t base = (size_t)blockIdx.x * 64 * C_;
    for (int idx = t; idx < 64 * C_; idx += 256)
      xT[base + idx] = Tl[idx / C_][idx % C_];
  }

  float nrm = nrmS[pl];
  int g = n >> 4, li = n & 15;
  float p2 = 0.f;
  #pragma unroll
  for (int s = 0; s < 6; s++) {
    int kslot = cg * 6 + s;          // 0..23
    int ks = kslot >> 2, kq = kslot & 3;
    union { short8 v; unsigned short u[8]; } ph, plo;
    #pragma unroll
    for (int j = 0; j < 8; j++) {
      float a = __fdiv_rn(Tl[pl][kslot * 8 + j], nrm);
      unsigned short h = f2bf(a);
      ph.u[j]  = h;
      plo.u[j] = f2bf(__fsub_rn(a, bf2f(h)));
      p2 = __fmaf_rn(a, a, p2);
    }
    size_t idx = (((size_t)b * 6 + ks) * 64 + g) * 64 + (kq * 16 + li);
    fragH[idx] = ph.v;
    fragL[idx] = plo.v;
  }
  red[cg][pl] = p2;
  __syncthreads();
  if (t < 64) {
    float sq = __fadd_rn(__fadd_rn(red[0][t], red[1][t]),
                         __fadd_rn(red[2][t], red[3][t]));
    int pp = blockIdx.x * 64 + t;
    sqp[(size_t)(pp / N_) * NP_ + (pp % N_)] = sq;
  }
}

// ---------------------------------------------------------------------------
// K2: MFMA KNN — R19/R22 structure (proven 103.5 us), unchanged.
// ---------------------------------------------------------------------------
__global__ __launch_bounds__(256) void knn_kernel(
    const short8* __restrict__ fragH, const short8* __restrict__ fragL,
    const float* __restrict__ sqp, int* __restrict__ nn9) {
  int wg = blockIdx.x;
  int r = wg & 7, j = wg >> 3;
  int b  = r + 8 * (j / 49);
  int qt = j % 49;
  int q0 = qt * 16;
  int t = threadIdx.x, lane = t & 63, w = t >> 6;

  __shared__ unsigned int dkS[16][DKW_];  // 53.5 KB keys
  __shared__ float qsqS[16];

  for (int i = t; i < 16 * 52; i += 256)
    dkS[i / 52][784 + i % 52] = 0xFFFFFFFFu;
  if (t < 16) qsqS[t] = sqp[(size_t)b * NP_ + q0 + t];
  __syncthreads();

  const float* sqb = sqp + (size_t)b * NP_;
  const short8* fH = fragH + (size_t)b * 6 * 64 * 64;
  const short8* fL = fragL + (size_t)b * 6 * 64 * 64;

  short8 aH[6], aL[6];
  #pragma unroll
  for (int ks = 0; ks < 6; ks++) {
    aH[ks] = fH[((size_t)ks * 64 + qt) * 64 + lane];
    aL[ks] = fL[((size_t)ks * 64 + qt) * 64 + lane];
  }

  int colL = lane & 15, rq = lane >> 4;
  const int wstart = (w == 0) ? 0 : (w == 1) ? 13 : (w == 2) ? 26 : 39;
  const int wend   = (w == 0) ? 13 : (w == 1) ? 26 : (w == 2) ? 39 : 49;

  int g = wstart;
  for (; g + 1 < wend; g += 2) {
    int g0 = g, g1 = g + 1;
    short8 B0h[6], B0l[6], B1h[6], B1l[6];
    #pragma unroll
    for (int ks = 0; ks < 6; ks++) {
      B0h[ks] = fH[((size_t)ks * 64 + g0) * 64 + lane];
      B0l[ks] = fL[((size_t)ks * 64 + g0) * 64 + lane];
      B1h[ks] = fH[((size_t)ks * 64 + g1) * 64 + lane];
      B1l[ks] = fL[((size_t)ks * 64 + g1) * 64 + lane];
    }
    float cs0 = sqb[g0 * 16 + colL];
    float cs1 = sqb[g1 * 16 + colL];
    f32x4 a00 = {0.f, 0.f, 0.f, 0.f}, a01 = a00, a02 = a00;
    f32x4 a10 = a00, a11 = a00, a12 = a00;
    #pragma unroll
    for (int ks = 0; ks < 6; ks++) {
      a00 = __builtin_amdgcn_mfma_f32_16x16x32_bf16(aH[ks], B0h[ks], a00, 0, 0, 0);
      a01 = __builtin_amdgcn_mfma_f32_16x16x32_bf16(aH[ks], B0l[ks], a01, 0, 0, 0);
      a02 = __builtin_amdgcn_mfma_f32_16x16x32_bf16(aL[ks], B0h[ks], a02, 0, 0, 0);
      a10 = __builtin_amdgcn_mfma_f32_16x16x32_bf16(aH[ks], B1h[ks], a10, 0, 0, 0);
      a11 = __builtin_amdgcn_mfma_f32_16x16x32_bf16(aH[ks], B1l[ks], a11, 0, 0, 0);
      a12 = __builtin_amdgcn_mfma_f32_16x16x32_bf16(aL[ks], B1h[ks], a12, 0, 0, 0);
    }
    #pragma unroll
    for (int rr = 0; rr < 4; rr++) {
      int row = rq * 4 + rr;
      float qs = qsqS[row];
      float g0v = __fadd_rn(__fadd_rn(a00[rr], a01[rr]), a02[rr]);
      float g1v = __fadd_rn(__fadd_rn(a10[rr], a11[rr]), a12[rr]);
      float d0 = __fadd_rn(__fsub_rn(qs, __fmul_rn(2.0f, g0v)), cs0);
      float d1 = __fadd_rn(__fsub_rn(qs, __fmul_rn(2.0f, g1v)), cs1);
      dkS[row][g0 * 16 + colL] = ford(d0);
      dkS[row][g1 * 16 + colL] = ford(d1);
    }
  }
  if (g < wend) {                       // odd tail: single group
    int g0 = g;
    short8 B0h[6], B0l[6];
    #pragma unroll
    for (int ks = 0; ks < 6; ks++) {
      B0h[ks] = fH[((size_t)ks * 64 + g0) * 64 + lane];
      B0l[ks] = fL[((size_t)ks * 64 + g0) * 64 + lane];
    }
    float cs0 = sqb[g0 * 16 + colL];
    f32x4 a00 = {0.f, 0.f, 0.f, 0.f}, a01 = a00, a02 = a00;
    #pragma unroll
    for (int ks = 0; ks < 6; ks++) {
      a00 = __builtin_amdgcn_mfma_f32_16x16x32_bf16(aH[ks], B0h[ks], a00, 0, 0, 0);
      a01 = __builtin_amdgcn_mfma_f32_16x16x32_bf16(aH[ks], B0l[ks], a01, 0, 0, 0);
      a02 = __builtin_amdgcn_mfma_f32_16x16x32_bf16(aL[ks], B0h[ks], a02, 0, 0, 0);
    }
    #pragma unroll
    for (int rr = 0; rr < 4; rr++) {
      int row = rq * 4 + rr;
      float qs = qsqS[row];
      float g0v = __fadd_rn(__fadd_rn(a00[rr], a01[rr]), a02[rr]);
      float d0 = __fadd_rn(__fsub_rn(qs, __fmul_rn(2.0f, g0v)), cs0);
      dkS[row][g0 * 16 + colL] = ford(d0);
    }
  }
  __syncthreads();

  for (int s = 0; s < 4; s++) {
    int row = w * 4 + s;
    unsigned int bv = 0xFFFFFFFFu; int bi = lane;
    #pragma unroll
    for (int it = 0; it < 13; it++) {
      unsigned int k = dkS[row][lane + 64 * it];
      if (k < bv) { bv = k; bi = lane + 64 * it; }
    }
    int* o = nn9 + ((size_t)b * N_ + q0 + row) * K_;
    for (int kk = 0; kk < K_; kk++) {
      unsigned long long mk = ((unsigned long long)bv << 10) | (unsigned int)bi;
      #pragma unroll
      for (int off = 1; off < 64; off <<= 1) {
        unsigned long long v2 = __shfl_xor(mk, off);
        mk = v2 < mk ? v2 : mk;
      }
      int widx = (int)(mk & 1023u);
      if (lane == 0) o[kk] = widx;
      if ((widx & 63) == lane) {
        dkS[row][widx] = 0xFFFFFFFFu;
        bv = 0xFFFFFFFFu; bi = lane;
        #pragma unroll
        for (int it = 0; it < 13; it++) {
          unsigned int k = dkS[row][lane + 64 * it];
          if (k < bv) { bv = k; bi = lane + 64 * it; }
        }
      }
    }
  }
}

// ---------------------------------------------------------------------------
// K3: FUSED gather (via xT) + max-rel + grouped conv; outpre stored BF16.
//  BN psums computed from exact fp32 registers (unchanged).
// ---------------------------------------------------------------------------
__global__ __launch_bounds__(256) void fconv_kernel(
    const float* __restrict__ xT, const int* __restrict__ nn9,
    const float* __restrict__ w, const float* __restrict__ bias,
    unsigned short* __restrict__ outpre, float* __restrict__ psum,
    float* __restrict__ pss) {
  int nt = blockIdx.x;
  int g  = blockIdx.y;
  int b  = blockIdx.z;
  int n0 = nt * 112;
  int t = threadIdx.x;

  __shared__ float Wl[48][97];
  __shared__ float Hl[96][112];
  __shared__ unsigned short Il[112][K_];

  const int* isrc = nn9 + ((size_t)b * N_ + n0) * K_;
  for (int i = t; i < 112 * K_; i += 256)
    Il[i / K_][i % K_] = (unsigned short)isrc[i];
  const float* wsrc0 = w + (size_t)(g * 96) * 96;
  for (int i = t; i < 48 * 96; i += 256) Wl[i / 96][i % 96] = wsrc0[i];
  __syncthreads();

  if (t < 224) {
    int nl = t >> 1, half = t & 1;
    const float* xrow = xT + ((size_t)b * N_ + n0 + nl) * C_ + g * 48 + half * 24;
    float xv[24], mx[24];
    #pragma unroll
    for (int j = 0; j < 24; j += 4) {
      float4 v = *(const float4*)(xrow + j);
      xv[j] = v.x; xv[j + 1] = v.y; xv[j + 2] = v.z; xv[j + 3] = v.w;
      mx[j] = -1e30f; mx[j + 1] = -1e30f; mx[j + 2] = -1e30f; mx[j + 3] = -1e30f;
    }
    #pragma unroll
    for (int k = 0; k < K_; k++) {
      int idx = Il[nl][k];
      const float* nrow = xT + ((size_t)b * N_ + idx) * C_ + g * 48 + half * 24;
      #pragma unroll
      for (int j = 0; j < 24; j += 4) {
        float4 v = *(const float4*)(nrow + j);
        mx[j]     = fmaxf(mx[j], v.x);
        mx[j + 1] = fmaxf(mx[j + 1], v.y);
        mx[j + 2] = fmaxf(mx[j + 2], v.z);
        mx[j + 3] = fmaxf(mx[j + 3], v.w);
      }
    }
    #pragma unroll
    for (int j = 0; j < 24; j++) {
      int cl = half * 24 + j;
      Hl[2 * cl][nl]     = xv[j];
      Hl[2 * cl + 1][nl] = mx[j] - xv[j];
    }
  }
  __syncthreads();

  int tx = t & 15, ty = t >> 4;
  int tidx = b * 7 + nt;

  for (int half = 0; half < 2; half++) {
    float o[3][7];
    #pragma unroll
    for (int i = 0; i < 3; i++)
      #pragma unroll
      for (int j = 0; j < 7; j++) o[i][j] = 0.f;

    for (int k = 0; k < 96; k++) {
      float w0 = Wl[ty * 3 + 0][k];
      float w1 = Wl[ty * 3 + 1][k];
      float w2 = Wl[ty * 3 + 2][k];
      #pragma unroll
      for (int j = 0; j < 7; j++) {
        float hv = Hl[k][tx * 7 + j];
        o[0][j] = __fmaf_rn(w0, hv, o[0][j]);
        o[1][j] = __fmaf_rn(w1, hv, o[1][j]);
        o[2][j] = __fmaf_rn(w2, hv, o[2][j]);
      }
    }

    #pragma unroll
    for (int i = 0; i < 3; i++) {
      int co = g * 96 + half * 48 + ty * 3 + i;
      float bv = bias[co];
      float s = 0.f, s2 = 0.f;
      unsigned short* orow =
          outpre + ((size_t)b * COUT_ + co) * N_ + n0 + tx * 7;
      #pragma unroll
      for (int j = 0; j < 7; j++) {
        float v = o[i][j] + bv;
        orow[j] = f2bf(v);
        s += v; s2 += v * v;
      }
      #pragma unroll
      for (int off = 1; off < 16; off <<= 1) {
        s  += __shfl_xor(s, off);
        s2 += __shfl_xor(s2, off);
      }
      if (tx == 0) {
        psum[co * NTILES_ + tidx] = s;
        pss [co * NTILES_ + tidx] = s2;
      }
    }

    if (half == 0) {
      __syncthreads();
      const float* wsrc1 = w + (size_t)(g * 96 + 48) * 96;
      for (int i = t; i < 48 * 96; i += 256) Wl[i / 96][i % 96] = wsrc1[i];
      __syncthreads();
    }
  }
}

// ---------------------------------------------------------------------------
// K4: finalize BN stats -> per-channel affine a, b
// ---------------------------------------------------------------------------
__global__ __launch_bounds__(64) void stats_kernel(
    const float* __restrict__ psum, const float* __restrict__ pss,
    const float* __restrict__ gamma, const float* __restrict__ beta,
    float* __restrict__ af, float* __restrict__ bf) {
  int co = blockIdx.x;
  int l = threadIdx.x;
  double s = 0.0, s2 = 0.0;
  for (int i = l; i < NTILES_; i += 64) {
    s  += (double)psum[co * NTILES_ + i];
    s2 += (double)pss [co * NTILES_ + i];
  }
  #pragma unroll
  for (int o = 32; o > 0; o >>= 1) { s += __shfl_xor(s, o); s2 += __shfl_xor(s2, o); }
  if (l == 0) {
    const double cnt = (double)NPTS_;
    double mean = s / cnt;
    double var  = s2 / cnt - mean * mean;
    double rstd = 1.0 / sqrt(var + 1e-5);
    double a = (double)gamma[co] * rstd;
    af[co] = (float)a;
    bf[co] = (float)((double)beta[co] - mean * a);
  }
}

// ---------------------------------------------------------------------------
// K5: BN affine + exact GELU + fp32 store (8 elems/thread, bf16 input)
// ---------------------------------------------------------------------------
__global__ __launch_bounds__(256) void act_kernel(
    const unsigned short* __restrict__ outpre, const float* __restrict__ af,
    const float* __restrict__ bf, float* __restrict__ out) {
  size_t i = ((size_t)blockIdx.x * 256 + threadIdx.x) * 8;
  int co = (int)((i / N_) % COUT_);     // N_ % 8 == 0 -> co uniform
  float a = af[co], c = bf[co];
  union { uint4 u4; unsigned short us[8]; } pk;
  pk.u4 = *reinterpret_cast<const uint4*>(outpre + i);
  const float is2 = 0.70710678118654752f;
  float r[8];
  #pragma unroll
  for (int j = 0; j < 8; j++) {
    float y = __fmaf_rn(a, bf2f(pk.us[j]), c);
    r[j] = 0.5f * y * (1.0f + erff(y * is2));
  }
  float4 r0 = {r[0], r[1], r[2], r[3]};
  float4 r1 = {r[4], r[5], r[6], r[7]};
  *reinterpret_cast<float4*>(out + i) = r0;
  *reinterpret_cast<float4*>(out + i + 4) = r1;
}

// ---------------------------------------------------------------------------
extern "C" void kernel_launch(void* const* d_in, const int* in_sizes, int n_in,
                              void* d_out, int out_size, void* d_ws, size_t ws_size,
                              hipStream_t stream) {
  const float* x      = (const float*)d_in[0];
  const float* conv_w = (const float*)d_in[1];
  const float* conv_b = (const float*)d_in[2];
  const float* gamma  = (const float*)d_in[3];
  const float* beta   = (const float*)d_in[4];
  float* out = (float*)d_out;

  // ws layout (float offsets), peak ~60 MB:
  //  [0, 6291456)   frags (norm->knn)  /  outpre bf16 [0, 4816896) (fconv->act)
  //  [9633792, ...] sqp | nn9 | xT | psum | pss | af | bf
  float* buf0 = (float*)d_ws;
  short8* fragH = (short8*)buf0;                         // [0, 3145728)
  short8* fragL = (short8*)(buf0 + 3145728);             // [3145728, 6291456)
  unsigned short* outpre = (unsigned short*)buf0;        // overlay (frags dead)
  float*  sqp   = buf0 + 9633792;                        // 32768
  int*    nn9   = (int*)(buf0 + 9666560);                // 225792
  float*  xT    = buf0 + 9892352;                        // 4816896
  float*  psum  = buf0 + 14709248;                       // 86016
  float*  pss   = psum + COUT_ * NTILES_;                // 86016
  float*  af    = pss + COUT_ * NTILES_;
  float*  bfv   = af + COUT_;

  hipLaunchKernelGGL(norm_kernel, dim3(NPTS_ / 64), dim3(256), 0, stream,
                     x, fragH, fragL, sqp, xT);
  hipLaunchKernelGGL(knn_kernel, dim3(49 * B_), dim3(256), 0, stream,
                     fragH, fragL, sqp, nn9);
  hipLaunchKernelGGL(fconv_kernel, dim3(7, 4, B_), dim3(256), 0, stream,
                     xT, nn9, conv_w, conv_b, outpre, psum, pss);
  hipLaunchKernelGGL(stats_kernel, dim3(COUT_), dim3(64), 0, stream,
                     psum, pss, gamma, beta, af, bfv);
  hipLaunchKernelGGL(act_kernel, dim3((B_ * COUT_ * N_) / (256 * 8)), dim3(256), 0, stream,
                     outpre, af, bfv, out);
}

// Round 24
// 189.486 us; speedup vs baseline: 1.1982x; 1.0152x over previous
//
#include <hip/hip_runtime.h>

#define B_    32
#define C_    192
#define N_    784
#define NP_   1024        // sqp row stride (pad never read)
#define K_    9
#define COUT_ 384
#define NPTS_ (B_ * N_)   // 25088
#define NTILES_ 224       // 32 b * 7 ntiles
#define DKW_  836         // dkS row stride (>= 13*64=832)

typedef __attribute__((ext_vector_type(8))) short short8;   // 8 bf16 = 4 VGPR
typedef __attribute__((ext_vector_type(4))) float f32x4;    // MFMA acc

// ordered-uint transform: monotone map float -> uint
__device__ __forceinline__ unsigned int ford(float f) {
  unsigned int u = __float_as_uint(f);
  return u ^ ((u & 0x80000000u) ? 0xFFFFFFFFu : 0x80000000u);
}
// fp32 -> bf16 (RNE)
__device__ __forceinline__ unsigned short f2bf(float f) {
  unsigned int u = __float_as_uint(f);
  u += 0x7FFFu + ((u >> 16) & 1u);
  return (unsigned short)(u >> 16);
}
__device__ __forceinline__ float bf2f(unsigned short h) {
  return __uint_as_float(((unsigned int)h) << 16);
}

// ---------------------------------------------------------------------------
// K1: norm + frag pack + coalesced xT via LDS transpose (proven R23).
// ---------------------------------------------------------------------------
__global__ __launch_bounds__(256) void norm_kernel(
    const float* __restrict__ x, short8* __restrict__ fragH,
    short8* __restrict__ fragL, float* __restrict__ sqp,
    float* __restrict__ xT) {
  int t = threadIdx.x;
  int pl = t & 63, cg = t >> 6;
  int p = blockIdx.x * 64 + pl;
  int b = p / N_, n = p % N_;
  const float* xb = x + (size_t)b * C_ * N_ + n;

  __shared__ float Tl[64][193];   // 49.4 KB
  __shared__ float red[4][64];
  __shared__ float nrmS[64];

  float part = 0.f;
  #pragma unroll
  for (int j = 0; j < 48; j++) {
    float v = xb[(size_t)(cg * 48 + j) * N_];
    Tl[pl][cg * 48 + j] = v;
    part = __fmaf_rn(v, v, part);
  }
  red[cg][pl] = part;
  __syncthreads();
  if (t < 64) {
    float ssq = __fadd_rn(__fadd_rn(red[0][t], red[1][t]),
                          __fadd_rn(red[2][t], red[3][t]));
    nrmS[t] = fmaxf(__fsqrt_rn(ssq), 1e-12f);
  }
  __syncthreads();

  {
    size_t base = (size_t)blockIdx.x * 64 * C_;
    for (int idx = t; idx < 64 * C_; idx += 256)
      xT[base + idx] = Tl[idx / C_][idx % C_];
  }

  float nrm = nrmS[pl];
  int g = n >> 4, li = n & 15;
  float p2 = 0.f;
  #pragma unroll
  for (int s = 0; s < 6; s++) {
    int kslot = cg * 6 + s;          // 0..23
    int ks = kslot >> 2, kq = kslot & 3;
    union { short8 v; unsigned short u[8]; } ph, plo;
    #pragma unroll
    for (int j = 0; j < 8; j++) {
      float a = __fdiv_rn(Tl[pl][kslot * 8 + j], nrm);
      unsigned short h = f2bf(a);
      ph.u[j]  = h;
      plo.u[j] = f2bf(__fsub_rn(a, bf2f(h)));
      p2 = __fmaf_rn(a, a, p2);
    }
    size_t idx = (((size_t)b * 6 + ks) * 64 + g) * 64 + (kq * 16 + li);
    fragH[idx] = ph.v;
    fragL[idx] = plo.v;
  }
  red[cg][pl] = p2;
  __syncthreads();
  if (t < 64) {
    float sq = __fadd_rn(__fadd_rn(red[0][t], red[1][t]),
                         __fadd_rn(red[2][t], red[3][t]));
    int pp = blockIdx.x * 64 + t;
    sqp[(size_t)(pp / N_) * NP_ + (pp % N_)] = sq;
  }
}

// ---------------------------------------------------------------------------
// K2: MFMA KNN — R19 structure (proven 103.5 us), unchanged.
// ---------------------------------------------------------------------------
__global__ __launch_bounds__(256) void knn_kernel(
    const short8* __restrict__ fragH, const short8* __restrict__ fragL,
    const float* __restrict__ sqp, int* __restrict__ nn9) {
  int wg = blockIdx.x;
  int r = wg & 7, j = wg >> 3;
  int b  = r + 8 * (j / 49);
  int qt = j % 49;
  int q0 = qt * 16;
  int t = threadIdx.x, lane = t & 63, w = t >> 6;

  __shared__ unsigned int dkS[16][DKW_];  // 53.5 KB keys
  __shared__ float qsqS[16];

  for (int i = t; i < 16 * 52; i += 256)
    dkS[i / 52][784 + i % 52] = 0xFFFFFFFFu;
  if (t < 16) qsqS[t] = sqp[(size_t)b * NP_ + q0 + t];
  __syncthreads();

  const float* sqb = sqp + (size_t)b * NP_;
  const short8* fH = fragH + (size_t)b * 6 * 64 * 64;
  const short8* fL = fragL + (size_t)b * 6 * 64 * 64;

  short8 aH[6], aL[6];
  #pragma unroll
  for (int ks = 0; ks < 6; ks++) {
    aH[ks] = fH[((size_t)ks * 64 + qt) * 64 + lane];
    aL[ks] = fL[((size_t)ks * 64 + qt) * 64 + lane];
  }

  int colL = lane & 15, rq = lane >> 4;
  const int wstart = (w == 0) ? 0 : (w == 1) ? 13 : (w == 2) ? 26 : 39;
  const int wend   = (w == 0) ? 13 : (w == 1) ? 26 : (w == 2) ? 39 : 49;

  int g = wstart;
  for (; g + 1 < wend; g += 2) {
    int g0 = g, g1 = g + 1;
    short8 B0h[6], B0l[6], B1h[6], B1l[6];
    #pragma unroll
    for (int ks = 0; ks < 6; ks++) {
      B0h[ks] = fH[((size_t)ks * 64 + g0) * 64 + lane];
      B0l[ks] = fL[((size_t)ks * 64 + g0) * 64 + lane];
      B1h[ks] = fH[((size_t)ks * 64 + g1) * 64 + lane];
      B1l[ks] = fL[((size_t)ks * 64 + g1) * 64 + lane];
    }
    float cs0 = sqb[g0 * 16 + colL];
    float cs1 = sqb[g1 * 16 + colL];
    f32x4 a00 = {0.f, 0.f, 0.f, 0.f}, a01 = a00, a02 = a00;
    f32x4 a10 = a00, a11 = a00, a12 = a00;
    #pragma unroll
    for (int ks = 0; ks < 6; ks++) {
      a00 = __builtin_amdgcn_mfma_f32_16x16x32_bf16(aH[ks], B0h[ks], a00, 0, 0, 0);
      a01 = __builtin_amdgcn_mfma_f32_16x16x32_bf16(aH[ks], B0l[ks], a01, 0, 0, 0);
      a02 = __builtin_amdgcn_mfma_f32_16x16x32_bf16(aL[ks], B0h[ks], a02, 0, 0, 0);
      a10 = __builtin_amdgcn_mfma_f32_16x16x32_bf16(aH[ks], B1h[ks], a10, 0, 0, 0);
      a11 = __builtin_amdgcn_mfma_f32_16x16x32_bf16(aH[ks], B1l[ks], a11, 0, 0, 0);
      a12 = __builtin_amdgcn_mfma_f32_16x16x32_bf16(aL[ks], B1h[ks], a12, 0, 0, 0);
    }
    #pragma unroll
    for (int rr = 0; rr < 4; rr++) {
      int row = rq * 4 + rr;
      float qs = qsqS[row];
      float g0v = __fadd_rn(__fadd_rn(a00[rr], a01[rr]), a02[rr]);
      float g1v = __fadd_rn(__fadd_rn(a10[rr], a11[rr]), a12[rr]);
      float d0 = __fadd_rn(__fsub_rn(qs, __fmul_rn(2.0f, g0v)), cs0);
      float d1 = __fadd_rn(__fsub_rn(qs, __fmul_rn(2.0f, g1v)), cs1);
      dkS[row][g0 * 16 + colL] = ford(d0);
      dkS[row][g1 * 16 + colL] = ford(d1);
    }
  }
  if (g < wend) {                       // odd tail: single group
    int g0 = g;
    short8 B0h[6], B0l[6];
    #pragma unroll
    for (int ks = 0; ks < 6; ks++) {
      B0h[ks] = fH[((size_t)ks * 64 + g0) * 64 + lane];
      B0l[ks] = fL[((size_t)ks * 64 + g0) * 64 + lane];
    }
    float cs0 = sqb[g0 * 16 + colL];
    f32x4 a00 = {0.f, 0.f, 0.f, 0.f}, a01 = a00, a02 = a00;
    #pragma unroll
    for (int ks = 0; ks < 6; ks++) {
      a00 = __builtin_amdgcn_mfma_f32_16x16x32_bf16(aH[ks], B0h[ks], a00, 0, 0, 0);
      a01 = __builtin_amdgcn_mfma_f32_16x16x32_bf16(aH[ks], B0l[ks], a01, 0, 0, 0);
      a02 = __builtin_amdgcn_mfma_f32_16x16x32_bf16(aL[ks], B0h[ks], a02, 0, 0, 0);
    }
    #pragma unroll
    for (int rr = 0; rr < 4; rr++) {
      int row = rq * 4 + rr;
      float qs = qsqS[row];
      float g0v = __fadd_rn(__fadd_rn(a00[rr], a01[rr]), a02[rr]);
      float d0 = __fadd_rn(__fsub_rn(qs, __fmul_rn(2.0f, g0v)), cs0);
      dkS[row][g0 * 16 + colL] = ford(d0);
    }
  }
  __syncthreads();

  for (int s = 0; s < 4; s++) {
    int row = w * 4 + s;
    unsigned int bv = 0xFFFFFFFFu; int bi = lane;
    #pragma unroll
    for (int it = 0; it < 13; it++) {
      unsigned int k = dkS[row][lane + 64 * it];
      if (k < bv) { bv = k; bi = lane + 64 * it; }
    }
    int* o = nn9 + ((size_t)b * N_ + q0 + row) * K_;
    for (int kk = 0; kk < K_; kk++) {
      unsigned long long mk = ((unsigned long long)bv << 10) | (unsigned int)bi;
      #pragma unroll
      for (int off = 1; off < 64; off <<= 1) {
        unsigned long long v2 = __shfl_xor(mk, off);
        mk = v2 < mk ? v2 : mk;
      }
      int widx = (int)(mk & 1023u);
      if (lane == 0) o[kk] = widx;
      if ((widx & 63) == lane) {
        dkS[row][widx] = 0xFFFFFFFFu;
        bv = 0xFFFFFFFFu; bi = lane;
        #pragma unroll
        for (int it = 0; it < 13; it++) {
          unsigned int k = dkS[row][lane + 64 * it];
          if (k < bv) { bv = k; bi = lane + 64 * it; }
        }
      }
    }
  }
}

// ---------------------------------------------------------------------------
// K3: FUSED gather + max-rel + grouped conv — MERGED halves (o[6][7]),
//  Wl resident as bf16[96][98] (18.8 KB). LDS bytes/FMA halved vs R23.
//  Weights pass through bf16 (predicted +~0.02 absmax).
// ---------------------------------------------------------------------------
__global__ __launch_bounds__(256) void fconv_kernel(
    const float* __restrict__ xT, const int* __restrict__ nn9,
    const float* __restrict__ w, const float* __restrict__ bias,
    unsigned short* __restrict__ outpre, float* __restrict__ psum,
    float* __restrict__ pss) {
  int nt = blockIdx.x;
  int g  = blockIdx.y;
  int b  = blockIdx.z;
  int n0 = nt * 112;
  int t = threadIdx.x;

  __shared__ unsigned short Wl[96][98];   // 18.8 KB bf16
  __shared__ float Hl[96][112];           // 43.0 KB
  __shared__ unsigned short Il[112][K_];  // 2.0 KB

  const int* isrc = nn9 + ((size_t)b * N_ + n0) * K_;
  for (int i = t; i < 112 * K_; i += 256)
    Il[i / K_][i % K_] = (unsigned short)isrc[i];
  const float* wsrc = w + (size_t)(g * 96) * 96;
  for (int i = t; i < 96 * 96; i += 256)
    Wl[i / 96][i % 96] = f2bf(wsrc[i]);
  __syncthreads();

  if (t < 224) {
    int nl = t >> 1, half = t & 1;
    const float* xrow = xT + ((size_t)b * N_ + n0 + nl) * C_ + g * 48 + half * 24;
    float xv[24], mx[24];
    #pragma unroll
    for (int j = 0; j < 24; j += 4) {
      float4 v = *(const float4*)(xrow + j);
      xv[j] = v.x; xv[j + 1] = v.y; xv[j + 2] = v.z; xv[j + 3] = v.w;
      mx[j] = -1e30f; mx[j + 1] = -1e30f; mx[j + 2] = -1e30f; mx[j + 3] = -1e30f;
    }
    #pragma unroll
    for (int k = 0; k < K_; k++) {
      int idx = Il[nl][k];
      const float* nrow = xT + ((size_t)b * N_ + idx) * C_ + g * 48 + half * 24;
      #pragma unroll
      for (int j = 0; j < 24; j += 4) {
        float4 v = *(const float4*)(nrow + j);
        mx[j]     = fmaxf(mx[j], v.x);
        mx[j + 1] = fmaxf(mx[j + 1], v.y);
        mx[j + 2] = fmaxf(mx[j + 2], v.z);
        mx[j + 3] = fmaxf(mx[j + 3], v.w);
      }
    }
    #pragma unroll
    for (int j = 0; j < 24; j++) {
      int cl = half * 24 + j;
      Hl[2 * cl][nl]     = xv[j];
      Hl[2 * cl + 1][nl] = mx[j] - xv[j];
    }
  }
  __syncthreads();

  int tx = t & 15, ty = t >> 4;
  int tidx = b * 7 + nt;

  float o[6][7];
  #pragma unroll
  for (int i = 0; i < 6; i++)
    #pragma unroll
    for (int j = 0; j < 7; j++) o[i][j] = 0.f;

  for (int k = 0; k < 96; k++) {
    float wv[6];
    #pragma unroll
    for (int i = 0; i < 6; i++) wv[i] = bf2f(Wl[ty * 6 + i][k]);
    #pragma unroll
    for (int j = 0; j < 7; j++) {
      float hv = Hl[k][tx * 7 + j];
      #pragma unroll
      for (int i = 0; i < 6; i++) o[i][j] = __fmaf_rn(wv[i], hv, o[i][j]);
    }
  }

  #pragma unroll
  for (int i = 0; i < 6; i++) {
    int co = g * 96 + ty * 6 + i;
    float bv = bias[co];
    float s = 0.f, s2 = 0.f;
    unsigned short* orow =
        outpre + ((size_t)b * COUT_ + co) * N_ + n0 + tx * 7;
    #pragma unroll
    for (int j = 0; j < 7; j++) {
      float v = o[i][j] + bv;
      orow[j] = f2bf(v);
      s += v; s2 += v * v;
    }
    #pragma unroll
    for (int off = 1; off < 16; off <<= 1) {
      s  += __shfl_xor(s, off);
      s2 += __shfl_xor(s2, off);
    }
    if (tx == 0) {
      psum[co * NTILES_ + tidx] = s;
      pss [co * NTILES_ + tidx] = s2;
    }
  }
}

// ---------------------------------------------------------------------------
// K4: finalize BN stats -> per-channel affine a, b
// ---------------------------------------------------------------------------
__global__ __launch_bounds__(64) void stats_kernel(
    const float* __restrict__ psum, const float* __restrict__ pss,
    const float* __restrict__ gamma, const float* __restrict__ beta,
    float* __restrict__ af, float* __restrict__ bf) {
  int co = blockIdx.x;
  int l = threadIdx.x;
  double s = 0.0, s2 = 0.0;
  for (int i = l; i < NTILES_; i += 64) {
    s  += (double)psum[co * NTILES_ + i];
    s2 += (double)pss [co * NTILES_ + i];
  }
  #pragma unroll
  for (int o = 32; o > 0; o >>= 1) { s += __shfl_xor(s, o); s2 += __shfl_xor(s2, o); }
  if (l == 0) {
    const double cnt = (double)NPTS_;
    double mean = s / cnt;
    double var  = s2 / cnt - mean * mean;
    double rstd = 1.0 / sqrt(var + 1e-5);
    double a = (double)gamma[co] * rstd;
    af[co] = (float)a;
    bf[co] = (float)((double)beta[co] - mean * a);
  }
}

// ---------------------------------------------------------------------------
// K5: BN affine + exact GELU + fp32 store (8 elems/thread, bf16 input)
// ---------------------------------------------------------------------------
__global__ __launch_bounds__(256) void act_kernel(
    const unsigned short* __restrict__ outpre, const float* __restrict__ af,
    const float* __restrict__ bf, float* __restrict__ out) {
  size_t i = ((size_t)blockIdx.x * 256 + threadIdx.x) * 8;
  int co = (int)((i / N_) % COUT_);     // N_ % 8 == 0 -> co uniform
  float a = af[co], c = bf[co];
  union { uint4 u4; unsigned short us[8]; } pk;
  pk.u4 = *reinterpret_cast<const uint4*>(outpre + i);
  const float is2 = 0.70710678118654752f;
  float r[8];
  #pragma unroll
  for (int j = 0; j < 8; j++) {
    float y = __fmaf_rn(a, bf2f(pk.us[j]), c);
    r[j] = 0.5f * y * (1.0f + erff(y * is2));
  }
  float4 r0 = {r[0], r[1], r[2], r[3]};
  float4 r1 = {r[4], r[5], r[6], r[7]};
  *reinterpret_cast<float4*>(out + i) = r0;
  *reinterpret_cast<float4*>(out + i + 4) = r1;
}

// ---------------------------------------------------------------------------
extern "C" void kernel_launch(void* const* d_in, const int* in_sizes, int n_in,
                              void* d_out, int out_size, void* d_ws, size_t ws_size,
                              hipStream_t stream) {
  const float* x      = (const float*)d_in[0];
  const float* conv_w = (const float*)d_in[1];
  const float* conv_b = (const float*)d_in[2];
  const float* gamma  = (const float*)d_in[3];
  const float* beta   = (const float*)d_in[4];
  float* out = (float*)d_out;

  float* buf0 = (float*)d_ws;
  short8* fragH = (short8*)buf0;                         // [0, 3145728)
  short8* fragL = (short8*)(buf0 + 3145728);             // [3145728, 6291456)
  unsigned short* outpre = (unsigned short*)buf0;        // overlay (frags dead)
  float*  sqp   = buf0 + 9633792;                        // 32768
  int*    nn9   = (int*)(buf0 + 9666560);                // 225792
  float*  xT    = buf0 + 9892352;                        // 4816896
  float*  psum  = buf0 + 14709248;                       // 86016
  float*  pss   = psum + COUT_ * NTILES_;                // 86016
  float*  af    = pss + COUT_ * NTILES_;
  float*  bfv   = af + COUT_;

  hipLaunchKernelGGL(norm_kernel, dim3(NPTS_ / 64), dim3(256), 0, stream,
                     x, fragH, fragL, sqp, xT);
  hipLaunchKernelGGL(knn_kernel, dim3(49 * B_), dim3(256), 0, stream,
                     fragH, fragL, sqp, nn9);
  hipLaunchKernelGGL(fconv_kernel, dim3(7, 4, B_), dim3(256), 0, stream,
                     xT, nn9, conv_w, conv_b, outpre, psum, pss);
  hipLaunchKernelGGL(stats_kernel, dim3(COUT_), dim3(64), 0, stream,
                     psum, pss, gamma, beta, af, bfv);
  hipLaunchKernelGGL(act_kernel, dim3((B_ * COUT_ * N_) / (256 * 8)), dim3(256), 0, stream,
                     outpre, af, bfv, out);
}

// Round 25
// 188.803 us; speedup vs baseline: 1.2025x; 1.0036x over previous
//
#include <hip/hip_runtime.h>

#define B_    32
#define C_    192
#define N_    784
#define NP_   1024        // sqp row stride (pad never read)
#define K_    9
#define COUT_ 384
#define NPTS_ (B_ * N_)   // 25088
#define NTILES_ 224       // 32 b * 7 ntiles
#define DKW_  836         // dkS row stride (>= 13*64=832)

typedef __attribute__((ext_vector_type(8))) short short8;   // 8 bf16 = 4 VGPR
typedef __attribute__((ext_vector_type(4))) float f32x4;    // MFMA acc

// ordered-uint transform: monotone map float -> uint
__device__ __forceinline__ unsigned int ford(float f) {
  unsigned int u = __float_as_uint(f);
  return u ^ ((u & 0x80000000u) ? 0xFFFFFFFFu : 0x80000000u);
}
// fp32 -> bf16 (RNE)
__device__ __forceinline__ unsigned short f2bf(float f) {
  unsigned int u = __float_as_uint(f);
  u += 0x7FFFu + ((u >> 16) & 1u);
  return (unsigned short)(u >> 16);
}
__device__ __forceinline__ float bf2f(unsigned short h) {
  return __uint_as_float(((unsigned int)h) << 16);
}

// ---------------------------------------------------------------------------
// K1: norm + frag pack + coalesced xT via LDS transpose (proven R23).
// ---------------------------------------------------------------------------
__global__ __launch_bounds__(256) void norm_kernel(
    const float* __restrict__ x, short8* __restrict__ fragH,
    short8* __restrict__ fragL, float* __restrict__ sqp,
    float* __restrict__ xT) {
  int t = threadIdx.x;
  int pl = t & 63, cg = t >> 6;
  int p = blockIdx.x * 64 + pl;
  int b = p / N_, n = p % N_;
  const float* xb = x + (size_t)b * C_ * N_ + n;

  __shared__ float Tl[64][193];   // 49.4 KB
  __shared__ float red[4][64];
  __shared__ float nrmS[64];

  float part = 0.f;
  #pragma unroll
  for (int j = 0; j < 48; j++) {
    float v = xb[(size_t)(cg * 48 + j) * N_];
    Tl[pl][cg * 48 + j] = v;
    part = __fmaf_rn(v, v, part);
  }
  red[cg][pl] = part;
  __syncthreads();
  if (t < 64) {
    float ssq = __fadd_rn(__fadd_rn(red[0][t], red[1][t]),
                          __fadd_rn(red[2][t], red[3][t]));
    nrmS[t] = fmaxf(__fsqrt_rn(ssq), 1e-12f);
  }
  __syncthreads();

  {
    size_t base = (size_t)blockIdx.x * 64 * C_;
    for (int idx = t; idx < 64 * C_; idx += 256)
      xT[base + idx] = Tl[idx / C_][idx % C_];
  }

  float nrm = nrmS[pl];
  int g = n >> 4, li = n & 15;
  float p2 = 0.f;
  #pragma unroll
  for (int s = 0; s < 6; s++) {
    int kslot = cg * 6 + s;          // 0..23
    int ks = kslot >> 2, kq = kslot & 3;
    union { short8 v; unsigned short u[8]; } ph, plo;
    #pragma unroll
    for (int j = 0; j < 8; j++) {
      float a = __fdiv_rn(Tl[pl][kslot * 8 + j], nrm);
      unsigned short h = f2bf(a);
      ph.u[j]  = h;
      plo.u[j] = f2bf(__fsub_rn(a, bf2f(h)));
      p2 = __fmaf_rn(a, a, p2);
    }
    size_t idx = (((size_t)b * 6 + ks) * 64 + g) * 64 + (kq * 16 + li);
    fragH[idx] = ph.v;
    fragL[idx] = plo.v;
  }
  red[cg][pl] = p2;
  __syncthreads();
  if (t < 64) {
    float sq = __fadd_rn(__fadd_rn(red[0][t], red[1][t]),
                         __fadd_rn(red[2][t], red[3][t]));
    int pp = blockIdx.x * 64 + t;
    sqp[(size_t)(pp / N_) * NP_ + (pp % N_)] = sq;
  }
}

// ---------------------------------------------------------------------------
// K2: MFMA KNN — R19 structure; launch_bounds(256, 2) frees the register
//  allocator to the TRUE budget (occupancy is LDS-pinned at 2 waves/SIMD,
//  so high VGPR is free) -> hoisted loads can stay in flight.
// ---------------------------------------------------------------------------
__global__ __launch_bounds__(256, 2) void knn_kernel(
    const short8* __restrict__ fragH, const short8* __restrict__ fragL,
    const float* __restrict__ sqp, int* __restrict__ nn9) {
  int wg = blockIdx.x;
  int r = wg & 7, j = wg >> 3;
  int b  = r + 8 * (j / 49);
  int qt = j % 49;
  int q0 = qt * 16;
  int t = threadIdx.x, lane = t & 63, w = t >> 6;

  __shared__ unsigned int dkS[16][DKW_];  // 53.5 KB keys
  __shared__ float qsqS[16];

  for (int i = t; i < 16 * 52; i += 256)
    dkS[i / 52][784 + i % 52] = 0xFFFFFFFFu;
  if (t < 16) qsqS[t] = sqp[(size_t)b * NP_ + q0 + t];
  __syncthreads();

  const float* sqb = sqp + (size_t)b * NP_;
  const short8* fH = fragH + (size_t)b * 6 * 64 * 64;
  const short8* fL = fragL + (size_t)b * 6 * 64 * 64;

  short8 aH[6], aL[6];
  #pragma unroll
  for (int ks = 0; ks < 6; ks++) {
    aH[ks] = fH[((size_t)ks * 64 + qt) * 64 + lane];
    aL[ks] = fL[((size_t)ks * 64 + qt) * 64 + lane];
  }

  int colL = lane & 15, rq = lane >> 4;
  const int wstart = (w == 0) ? 0 : (w == 1) ? 13 : (w == 2) ? 26 : 39;
  const int wend   = (w == 0) ? 13 : (w == 1) ? 26 : (w == 2) ? 39 : 49;

  int g = wstart;
  for (; g + 1 < wend; g += 2) {
    int g0 = g, g1 = g + 1;
    short8 B0h[6], B0l[6], B1h[6], B1l[6];
    #pragma unroll
    for (int ks = 0; ks < 6; ks++) {
      B0h[ks] = fH[((size_t)ks * 64 + g0) * 64 + lane];
      B0l[ks] = fL[((size_t)ks * 64 + g0) * 64 + lane];
      B1h[ks] = fH[((size_t)ks * 64 + g1) * 64 + lane];
      B1l[ks] = fL[((size_t)ks * 64 + g1) * 64 + lane];
    }
    float cs0 = sqb[g0 * 16 + colL];
    float cs1 = sqb[g1 * 16 + colL];
    f32x4 a00 = {0.f, 0.f, 0.f, 0.f}, a01 = a00, a02 = a00;
    f32x4 a10 = a00, a11 = a00, a12 = a00;
    #pragma unroll
    for (int ks = 0; ks < 6; ks++) {
      a00 = __builtin_amdgcn_mfma_f32_16x16x32_bf16(aH[ks], B0h[ks], a00, 0, 0, 0);
      a01 = __builtin_amdgcn_mfma_f32_16x16x32_bf16(aH[ks], B0l[ks], a01, 0, 0, 0);
      a02 = __builtin_amdgcn_mfma_f32_16x16x32_bf16(aL[ks], B0h[ks], a02, 0, 0, 0);
      a10 = __builtin_amdgcn_mfma_f32_16x16x32_bf16(aH[ks], B1h[ks], a10, 0, 0, 0);
      a11 = __builtin_amdgcn_mfma_f32_16x16x32_bf16(aH[ks], B1l[ks], a11, 0, 0, 0);
      a12 = __builtin_amdgcn_mfma_f32_16x16x32_bf16(aL[ks], B1h[ks], a12, 0, 0, 0);
    }
    #pragma unroll
    for (int rr = 0; rr < 4; rr++) {
      int row = rq * 4 + rr;
      float qs = qsqS[row];
      float g0v = __fadd_rn(__fadd_rn(a00[rr], a01[rr]), a02[rr]);
      float g1v = __fadd_rn(__fadd_rn(a10[rr], a11[rr]), a12[rr]);
      float d0 = __fadd_rn(__fsub_rn(qs, __fmul_rn(2.0f, g0v)), cs0);
      float d1 = __fadd_rn(__fsub_rn(qs, __fmul_rn(2.0f, g1v)), cs1);
      dkS[row][g0 * 16 + colL] = ford(d0);
      dkS[row][g1 * 16 + colL] = ford(d1);
    }
  }
  if (g < wend) {                       // odd tail: single group
    int g0 = g;
    short8 B0h[6], B0l[6];
    #pragma unroll
    for (int ks = 0; ks < 6; ks++) {
      B0h[ks] = fH[((size_t)ks * 64 + g0) * 64 + lane];
      B0l[ks] = fL[((size_t)ks * 64 + g0) * 64 + lane];
    }
    float cs0 = sqb[g0 * 16 + colL];
    f32x4 a00 = {0.f, 0.f, 0.f, 0.f}, a01 = a00, a02 = a00;
    #pragma unroll
    for (int ks = 0; ks < 6; ks++) {
      a00 = __builtin_amdgcn_mfma_f32_16x16x32_bf16(aH[ks], B0h[ks], a00, 0, 0, 0);
      a01 = __builtin_amdgcn_mfma_f32_16x16x32_bf16(aH[ks], B0l[ks], a01, 0, 0, 0);
      a02 = __builtin_amdgcn_mfma_f32_16x16x32_bf16(aL[ks], B0h[ks], a02, 0, 0, 0);
    }
    #pragma unroll
    for (int rr = 0; rr < 4; rr++) {
      int row = rq * 4 + rr;
      float qs = qsqS[row];
      float g0v = __fadd_rn(__fadd_rn(a00[rr], a01[rr]), a02[rr]);
      float d0 = __fadd_rn(__fsub_rn(qs, __fmul_rn(2.0f, g0v)), cs0);
      dkS[row][g0 * 16 + colL] = ford(d0);
    }
  }
  __syncthreads();

  for (int s = 0; s < 4; s++) {
    int row = w * 4 + s;
    unsigned int bv = 0xFFFFFFFFu; int bi = lane;
    #pragma unroll
    for (int it = 0; it < 13; it++) {
      unsigned int k = dkS[row][lane + 64 * it];
      if (k < bv) { bv = k; bi = lane + 64 * it; }
    }
    int* o = nn9 + ((size_t)b * N_ + q0 + row) * K_;
    for (int kk = 0; kk < K_; kk++) {
      unsigned long long mk = ((unsigned long long)bv << 10) | (unsigned int)bi;
      #pragma unroll
      for (int off = 1; off < 64; off <<= 1) {
        unsigned long long v2 = __shfl_xor(mk, off);
        mk = v2 < mk ? v2 : mk;
      }
      int widx = (int)(mk & 1023u);
      if (lane == 0) o[kk] = widx;
      if ((widx & 63) == lane) {
        dkS[row][widx] = 0xFFFFFFFFu;
        bv = 0xFFFFFFFFu; bi = lane;
        #pragma unroll
        for (int it = 0; it < 13; it++) {
          unsigned int k = dkS[row][lane + 64 * it];
          if (k < bv) { bv = k; bi = lane + 64 * it; }
        }
      }
    }
  }
}

// ---------------------------------------------------------------------------
// K3: FUSED gather + max-rel + grouped conv — merged halves, bf16 Wl (R24).
// ---------------------------------------------------------------------------
__global__ __launch_bounds__(256) void fconv_kernel(
    const float* __restrict__ xT, const int* __restrict__ nn9,
    const float* __restrict__ w, const float* __restrict__ bias,
    unsigned short* __restrict__ outpre, float* __restrict__ psum,
    float* __restrict__ pss) {
  int nt = blockIdx.x;
  int g  = blockIdx.y;
  int b  = blockIdx.z;
  int n0 = nt * 112;
  int t = threadIdx.x;

  __shared__ unsigned short Wl[96][98];   // 18.8 KB bf16
  __shared__ float Hl[96][112];           // 43.0 KB
  __shared__ unsigned short Il[112][K_];  // 2.0 KB

  const int* isrc = nn9 + ((size_t)b * N_ + n0) * K_;
  for (int i = t; i < 112 * K_; i += 256)
    Il[i / K_][i % K_] = (unsigned short)isrc[i];
  const float* wsrc = w + (size_t)(g * 96) * 96;
  for (int i = t; i < 96 * 96; i += 256)
    Wl[i / 96][i % 96] = f2bf(wsrc[i]);
  __syncthreads();

  if (t < 224) {
    int nl = t >> 1, half = t & 1;
    const float* xrow = xT + ((size_t)b * N_ + n0 + nl) * C_ + g * 48 + half * 24;
    float xv[24], mx[24];
    #pragma unroll
    for (int j = 0; j < 24; j += 4) {
      float4 v = *(const float4*)(xrow + j);
      xv[j] = v.x; xv[j + 1] = v.y; xv[j + 2] = v.z; xv[j + 3] = v.w;
      mx[j] = -1e30f; mx[j + 1] = -1e30f; mx[j + 2] = -1e30f; mx[j + 3] = -1e30f;
    }
    #pragma unroll
    for (int k = 0; k < K_; k++) {
      int idx = Il[nl][k];
      const float* nrow = xT + ((size_t)b * N_ + idx) * C_ + g * 48 + half * 24;
      #pragma unroll
      for (int j = 0; j < 24; j += 4) {
        float4 v = *(const float4*)(nrow + j);
        mx[j]     = fmaxf(mx[j], v.x);
        mx[j + 1] = fmaxf(mx[j + 1], v.y);
        mx[j + 2] = fmaxf(mx[j + 2], v.z);
        mx[j + 3] = fmaxf(mx[j + 3], v.w);
      }
    }
    #pragma unroll
    for (int j = 0; j < 24; j++) {
      int cl = half * 24 + j;
      Hl[2 * cl][nl]     = xv[j];
      Hl[2 * cl + 1][nl] = mx[j] - xv[j];
    }
  }
  __syncthreads();

  int tx = t & 15, ty = t >> 4;
  int tidx = b * 7 + nt;

  float o[6][7];
  #pragma unroll
  for (int i = 0; i < 6; i++)
    #pragma unroll
    for (int j = 0; j < 7; j++) o[i][j] = 0.f;

  for (int k = 0; k < 96; k++) {
    float wv[6];
    #pragma unroll
    for (int i = 0; i < 6; i++) wv[i] = bf2f(Wl[ty * 6 + i][k]);
    #pragma unroll
    for (int j = 0; j < 7; j++) {
      float hv = Hl[k][tx * 7 + j];
      #pragma unroll
      for (int i = 0; i < 6; i++) o[i][j] = __fmaf_rn(wv[i], hv, o[i][j]);
    }
  }

  #pragma unroll
  for (int i = 0; i < 6; i++) {
    int co = g * 96 + ty * 6 + i;
    float bv = bias[co];
    float s = 0.f, s2 = 0.f;
    unsigned short* orow =
        outpre + ((size_t)b * COUT_ + co) * N_ + n0 + tx * 7;
    #pragma unroll
    for (int j = 0; j < 7; j++) {
      float v = o[i][j] + bv;
      orow[j] = f2bf(v);
      s += v; s2 += v * v;
    }
    #pragma unroll
    for (int off = 1; off < 16; off <<= 1) {
      s  += __shfl_xor(s, off);
      s2 += __shfl_xor(s2, off);
    }
    if (tx == 0) {
      psum[co * NTILES_ + tidx] = s;
      pss [co * NTILES_ + tidx] = s2;
    }
  }
}

// ---------------------------------------------------------------------------
// K4: finalize BN stats -> per-channel affine a, b
// ---------------------------------------------------------------------------
__global__ __launch_bounds__(64) void stats_kernel(
    const float* __restrict__ psum, const float* __restrict__ pss,
    const float* __restrict__ gamma, const float* __restrict__ beta,
    float* __restrict__ af, float* __restrict__ bf) {
  int co = blockIdx.x;
  int l = threadIdx.x;
  double s = 0.0, s2 = 0.0;
  for (int i = l; i < NTILES_; i += 64) {
    s  += (double)psum[co * NTILES_ + i];
    s2 += (double)pss [co * NTILES_ + i];
  }
  #pragma unroll
  for (int o = 32; o > 0; o >>= 1) { s += __shfl_xor(s, o); s2 += __shfl_xor(s2, o); }
  if (l == 0) {
    const double cnt = (double)NPTS_;
    double mean = s / cnt;
    double var  = s2 / cnt - mean * mean;
    double rstd = 1.0 / sqrt(var + 1e-5);
    double a = (double)gamma[co] * rstd;
    af[co] = (float)a;
    bf[co] = (float)((double)beta[co] - mean * a);
  }
}

// ---------------------------------------------------------------------------
// K5: BN affine + exact GELU + fp32 store (8 elems/thread, bf16 input)
// ---------------------------------------------------------------------------
__global__ __launch_bounds__(256) void act_kernel(
    const unsigned short* __restrict__ outpre, const float* __restrict__ af,
    const float* __restrict__ bf, float* __restrict__ out) {
  size_t i = ((size_t)blockIdx.x * 256 + threadIdx.x) * 8;
  int co = (int)((i / N_) % COUT_);     // N_ % 8 == 0 -> co uniform
  float a = af[co], c = bf[co];
  union { uint4 u4; unsigned short us[8]; } pk;
  pk.u4 = *reinterpret_cast<const uint4*>(outpre + i);
  const float is2 = 0.70710678118654752f;
  float r[8];
  #pragma unroll
  for (int j = 0; j < 8; j++) {
    float y = __fmaf_rn(a, bf2f(pk.us[j]), c);
    r[j] = 0.5f * y * (1.0f + erff(y * is2));
  }
  float4 r0 = {r[0], r[1], r[2], r[3]};
  float4 r1 = {r[4], r[5], r[6], r[7]};
  *reinterpret_cast<float4*>(out + i) = r0;
  *reinterpret_cast<float4*>(out + i + 4) = r1;
}

// ---------------------------------------------------------------------------
extern "C" void kernel_launch(void* const* d_in, const int* in_sizes, int n_in,
                              void* d_out, int out_size, void* d_ws, size_t ws_size,
                              hipStream_t stream) {
  const float* x      = (const float*)d_in[0];
  const float* conv_w = (const float*)d_in[1];
  const float* conv_b = (const float*)d_in[2];
  const float* gamma  = (const float*)d_in[3];
  const float* beta   = (const float*)d_in[4];
  float* out = (float*)d_out;

  float* buf0 = (float*)d_ws;
  short8* fragH = (short8*)buf0;                         // [0, 3145728)
  short8* fragL = (short8*)(buf0 + 3145728);             // [3145728, 6291456)
  unsigned short* outpre = (unsigned short*)buf0;        // overlay (frags dead)
  float*  sqp   = buf0 + 9633792;                        // 32768
  int*    nn9   = (int*)(buf0 + 9666560);                // 225792
  float*  xT    = buf0 + 9892352;                        // 4816896
  float*  psum  = buf0 + 14709248;                       // 86016
  float*  pss   = psum + COUT_ * NTILES_;                // 86016
  float*  af    = pss + COUT_ * NTILES_;
  float*  bfv   = af + COUT_;

  hipLaunchKernelGGL(norm_kernel, dim3(NPTS_ / 64), dim3(256), 0, stream,
                     x, fragH, fragL, sqp, xT);
  hipLaunchKernelGGL(knn_kernel, dim3(49 * B_), dim3(256), 0, stream,
                     fragH, fragL, sqp, nn9);
  hipLaunchKernelGGL(fconv_kernel, dim3(7, 4, B_), dim3(256), 0, stream,
                     xT, nn9, conv_w, conv_b, outpre, psum, pss);
  hipLaunchKernelGGL(stats_kernel, dim3(COUT_), dim3(64), 0, stream,
                     psum, pss, gamma, beta, af, bfv);
  hipLaunchKernelGGL(act_kernel, dim3((B_ * COUT_ * N_) / (256 * 8)), dim3(256), 0, stream,
                     outpre, af, bfv, out);
}